// Round 2
// baseline (4994.889 us; speedup 1.0000x reference)
//
#include <hip/hip_runtime.h>

// All inputs/outputs are fp32 (reference setup_inputs is float32).
// Workspace layout: 6 units of 16384*512 floats = 201.3 MB total.
//   unit0: Q / r1 / r2     unit1: K / ln1     unit2: V / (mid..) / ln2
//   unit3: headR (mid..)   unit4: h0 (mid..)  unit5: Wq/Wk/Wv repack, (mid..)
// mid [16384,2048] spans units 2..5 (all dead by FFN1 time).

// ---------------------------------------------------------------------------
// Epilogue modes for the generic tiled GEMM
#define EP_EMB       0   // + bias + positional encoding
#define EP_NONE      1   // plain store
#define EP_RES       2   // + residual
#define EP_BIAS_RELU 3   // + bias, relu
#define EP_BIAS_RES  4   // + bias + residual

// C[M,N] = A[M,K] @ B[K,N] (+ epilogue). fp32 row-major, fp32 accum.
// 64x64 tile, 256 threads, 4x4 micro-tile per thread, K-tile 16.
template <int EP>
__global__ __launch_bounds__(256) void gemm_kernel(
    const float* __restrict__ A, const float* __restrict__ B,
    const float* __restrict__ bias, const float* __restrict__ res,
    float* __restrict__ C, int M, int N, int K)
{
    __shared__ float As[16][68];  // [kk][m]; 68*4=272B row stride (16B-aligned)
    __shared__ float Bs[16][68];  // [kk][n]
    const int tid = threadIdx.x;
    const int row0 = blockIdx.x * 64;
    const int col0 = blockIdx.y * 64;
    const int ty = tid >> 4, tx = tid & 15;

    float acc[4][4] = {};

    for (int k0 = 0; k0 < K; k0 += 16) {
        #pragma unroll
        for (int l = 0; l < 4; ++l) {
            int e = tid + l * 256;          // 0..1023 over 64x16 A tile
            int m = e >> 4, kk = e & 15;
            As[kk][m] = A[(size_t)(row0 + m) * K + k0 + kk];
        }
        #pragma unroll
        for (int l = 0; l < 4; ++l) {
            int e = tid + l * 256;          // 0..1023 over 16x64 B tile
            int kk = e >> 6, n = e & 63;
            Bs[kk][n] = B[(size_t)(k0 + kk) * N + col0 + n];
        }
        __syncthreads();
        #pragma unroll
        for (int kk = 0; kk < 16; ++kk) {
            float4 a4 = *(const float4*)&As[kk][ty * 4];
            float4 b4 = *(const float4*)&Bs[kk][tx * 4];
            float a[4] = {a4.x, a4.y, a4.z, a4.w};
            float b[4] = {b4.x, b4.y, b4.z, b4.w};
            #pragma unroll
            for (int i = 0; i < 4; ++i)
                #pragma unroll
                for (int j = 0; j < 4; ++j)
                    acc[i][j] += a[i] * b[j];
        }
        __syncthreads();
    }

    #pragma unroll
    for (int i = 0; i < 4; ++i) {
        int row = row0 + ty * 4 + i;
        #pragma unroll
        for (int j = 0; j < 4; ++j) {
            int col = col0 + tx * 4 + j;
            float v = acc[i][j];
            if constexpr (EP == EP_EMB) {
                v += bias[col];
                int s = row & 1023;  // row = b*1024 + s
                float div = expf((float)(col & ~1) * (-9.210340371976184f / 512.0f));
                float ang = (float)s * div;
                v += (col & 1) ? cosf(ang) : sinf(ang);
            } else if constexpr (EP == EP_RES) {
                v += res[(size_t)row * N + col];
            } else if constexpr (EP == EP_BIAS_RELU) {
                v += bias[col];
                v = fmaxf(v, 0.0f);
            } else if constexpr (EP == EP_BIAS_RES) {
                v += bias[col] + res[(size_t)row * N + col];
            }
            C[(size_t)row * N + col] = v;
        }
    }
}

// ---------------------------------------------------------------------------
// Repack W[H,D,DK] -> Wr[D, H*DK] so QKV projection is a single [512,512] GEMM.
__global__ __launch_bounds__(256) void repack_kernel(const float* __restrict__ W,
                                                     float* __restrict__ Wr)
{
    int idx = blockIdx.x * 256 + threadIdx.x;   // idx = k*512 + h*128 + e
    int k = idx >> 9;
    int he = idx & 511;
    int h = he >> 7, e = he & 127;
    Wr[idx] = W[(size_t)(h * 512 + k) * 128 + e];
}

// ---------------------------------------------------------------------------
// Fused attention: one block = (b, h, 8 q-rows). Scores fp32 in LDS,
// two-pass softmax, K/V staged in tiles of 32 rows. Q/K/V layout [B*S, H*DK].
// Output O in [B,H,S,DK] contiguous layout (== reference's raw reshape).
__global__ __launch_bounds__(256) void attn_kernel(
    const float* __restrict__ Qm, const float* __restrict__ Km,
    const float* __restrict__ Vm, float* __restrict__ O)
{
    __shared__ float sc[8][1024];   // 32 KB scores
    __shared__ float kv[32][129];   // stride 129 -> conflict-free dot reads
    __shared__ float qs[8][129];
    __shared__ float red[8][33];

    const int tid = threadIdx.x;
    const int qc = blockIdx.x;      // 0..127 (8 rows each)
    const int h  = blockIdx.y;      // 0..3
    const int b  = blockIdx.z;      // 0..15
    const size_t bh_off = (size_t)b * 1024 * 512 + (size_t)h * 128;  // + s*512

    // load Q rows, pre-scaled by 1/sqrt(128)
    {
        int idx = tid * 4;                       // 8*128 = 1024 elems
        int r = idx >> 7, e0 = idx & 127;
        const float* qp = Qm + bh_off + (size_t)(qc * 8 + r) * 512 + e0;
        #pragma unroll
        for (int j = 0; j < 4; ++j)
            qs[r][e0 + j] = qp[j] * 0.08838834764831845f;
    }
    __syncthreads();

    // scores: S[r][t] = q_r . k_t
    for (int kt = 0; kt < 32; ++kt) {
        #pragma unroll
        for (int c = 0; c < 2; ++c) {
            int idx = (c * 256 + tid) * 8;       // 32*128 = 4096 elems
            int rr = idx >> 7, e0 = idx & 127;
            const float* kp = Km + bh_off + (size_t)(kt * 32 + rr) * 512 + e0;
            #pragma unroll
            for (int j = 0; j < 8; ++j) kv[rr][e0 + j] = kp[j];
        }
        __syncthreads();
        int r = tid >> 5, tt = tid & 31;
        float dot = 0.0f;
        for (int d = 0; d < 128; ++d) dot += qs[r][d] * kv[tt][d];
        sc[r][kt * 32 + tt] = dot;
        __syncthreads();
    }

    // softmax over each row of sc
    const int r = tid >> 5, c = tid & 31;
    float m = -1e30f;
    for (int j = c; j < 1024; j += 32) m = fmaxf(m, sc[r][j]);
    red[r][c] = m;
    __syncthreads();
    if (tid < 8) {
        float mm = -1e30f;
        for (int i = 0; i < 32; ++i) mm = fmaxf(mm, red[tid][i]);
        red[tid][32] = mm;
    }
    __syncthreads();
    float rowmax = red[r][32];
    float s = 0.0f;
    for (int j = c; j < 1024; j += 32) {
        float e = expf(sc[r][j] - rowmax);
        sc[r][j] = e;
        s += e;
    }
    __syncthreads();
    red[r][c] = s;
    __syncthreads();
    if (tid < 8) {
        float t = 0.0f;
        for (int i = 0; i < 32; ++i) t += red[tid][i];
        red[tid][32] = t;
    }
    __syncthreads();
    const float inv = 1.0f / red[r][32];

    // PV: out[r][e] = sum_t p[r][t] * V[t][e]
    const int e0 = (tid & 31) * 4;
    const int rr2 = tid >> 5;
    float acc[4] = {0.f, 0.f, 0.f, 0.f};
    for (int vt = 0; vt < 32; ++vt) {
        __syncthreads();  // previous kv tile fully consumed
        #pragma unroll
        for (int cc = 0; cc < 2; ++cc) {
            int idx = (cc * 256 + tid) * 8;
            int vr = idx >> 7, ee = idx & 127;
            const float* vp = Vm + bh_off + (size_t)(vt * 32 + vr) * 512 + ee;
            #pragma unroll
            for (int j = 0; j < 8; ++j) kv[vr][ee + j] = vp[j];
        }
        __syncthreads();
        for (int tt = 0; tt < 32; ++tt) {
            float p = sc[rr2][vt * 32 + tt];
            #pragma unroll
            for (int j = 0; j < 4; ++j) acc[j] += p * kv[tt][e0 + j];
        }
    }
    // store into [B,H,S,DK] flat (raw-reshape-compatible)
    size_t obase = ((size_t)(b * 4 + h) * 1024 + (qc * 8 + rr2)) * 128 + e0;
    #pragma unroll
    for (int j = 0; j < 4; ++j) O[obase + j] = acc[j] * inv;
}

// ---------------------------------------------------------------------------
// Row LayerNorm over 512 features. One block per row, 2 elems/thread.
__global__ __launch_bounds__(256) void ln_kernel(const float* __restrict__ in,
                                                 const float* __restrict__ g,
                                                 const float* __restrict__ bta,
                                                 float* __restrict__ out)
{
    const size_t row = blockIdx.x;
    const int tid = threadIdx.x;
    float v0 = in[row * 512 + tid];
    float v1 = in[row * 512 + 256 + tid];
    __shared__ float ss[256], sq[256];
    ss[tid] = v0 + v1;
    sq[tid] = v0 * v0 + v1 * v1;
    __syncthreads();
    for (int o = 128; o > 0; o >>= 1) {
        if (tid < o) { ss[tid] += ss[tid + o]; sq[tid] += sq[tid + o]; }
        __syncthreads();
    }
    float mu = ss[0] * (1.0f / 512.0f);
    float var = sq[0] * (1.0f / 512.0f) - mu * mu;
    float rstd = rsqrtf(var + 1e-5f);
    out[row * 512 + tid]       = (v0 - mu) * rstd * g[tid] + bta[tid];
    out[row * 512 + 256 + tid] = (v1 - mu) * rstd * g[tid + 256] + bta[tid + 256];
}

// ---------------------------------------------------------------------------
// MaxPool1d(16) over features + FC[32768,2] + log_softmax. One block per batch.
__global__ __launch_bounds__(256) void final_kernel(const float* __restrict__ ln2,
                                                    const float* __restrict__ fcw,
                                                    const float* __restrict__ fcb,
                                                    float* __restrict__ out)
{
    const int b = blockIdx.x;
    const int tid = threadIdx.x;
    float a0 = 0.0f, a1 = 0.0f;
    for (int m = tid; m < 32768; m += 256) {
        int s = m >> 5, j = m & 31;     // pooled[b, s*32 + j]
        const float* p = ln2 + ((size_t)(b * 1024 + s) * 512) + j * 16;
        float mx = -1e30f;
        #pragma unroll
        for (int t = 0; t < 16; ++t) mx = fmaxf(mx, p[t]);
        a0 += mx * fcw[2 * m];
        a1 += mx * fcw[2 * m + 1];
    }
    __shared__ float r0[256], r1[256];
    r0[tid] = a0; r1[tid] = a1;
    __syncthreads();
    for (int o = 128; o > 0; o >>= 1) {
        if (tid < o) { r0[tid] += r0[tid + o]; r1[tid] += r1[tid + o]; }
        __syncthreads();
    }
    if (tid == 0) {
        float z0 = r0[0] + fcb[0];
        float z1 = r1[0] + fcb[1];
        float mx = fmaxf(z0, z1);
        float lse = mx + logf(expf(z0 - mx) + expf(z1 - mx));
        out[b * 2 + 0] = z0 - lse;
        out[b * 2 + 1] = z1 - lse;
    }
}

// ---------------------------------------------------------------------------
extern "C" void kernel_launch(void* const* d_in, const int* in_sizes, int n_in,
                              void* d_out, int out_size, void* d_ws, size_t ws_size,
                              hipStream_t stream)
{
    const float* x     = (const float*)d_in[0];
    const float* emb_w = (const float*)d_in[1];
    const float* emb_b = (const float*)d_in[2];
    const float* WQ    = (const float*)d_in[3];
    const float* WK    = (const float*)d_in[4];
    const float* WV    = (const float*)d_in[5];
    const float* WO    = (const float*)d_in[6];
    const float* g1    = (const float*)d_in[7];
    const float* b1    = (const float*)d_in[8];
    const float* l1w   = (const float*)d_in[9];
    const float* l1b   = (const float*)d_in[10];
    const float* l2w   = (const float*)d_in[11];
    const float* l2b   = (const float*)d_in[12];
    const float* g2    = (const float*)d_in[13];
    const float* b2    = (const float*)d_in[14];
    const float* fcw   = (const float*)d_in[15];
    const float* fcb   = (const float*)d_in[16];
    float* out = (float*)d_out;

    char* ws = (char*)d_ws;
    const size_t U = (size_t)16384 * 512 * 4;   // 33.55 MB per activation unit
    float* Q     = (float*)(ws + 0 * U);
    float* Kb    = (float*)(ws + 1 * U);
    float* V     = (float*)(ws + 2 * U);
    float* headR = (float*)(ws + 3 * U);
    float* h0    = (float*)(ws + 4 * U);
    float* mid   = (float*)(ws + 2 * U);        // [16384,2048] over dead units 2..5
    float* r1    = Q;                           // Q dead after attention
    float* ln1   = Kb;                          // K dead after attention
    float* r2    = Q;                           // r1 dead after LN1
    float* ln2   = (float*)(ws + 2 * U);        // mid dead after FFN2
    float* Wqr   = (float*)(ws + 5 * U);        // unit5 dead until FFN1's mid
    float* Wkr   = (float*)(ws + 5 * U + (size_t)512 * 512 * 4);
    float* Wvr   = (float*)(ws + 5 * U + (size_t)2 * 512 * 512 * 4);

    const int M = 16384;

    // repack per-head weights
    repack_kernel<<<1024, 256, 0, stream>>>(WQ, Wqr);
    repack_kernel<<<1024, 256, 0, stream>>>(WK, Wkr);
    repack_kernel<<<1024, 256, 0, stream>>>(WV, Wvr);

    // 1) h0 = x @ emb_w + emb_b + pos_encoding
    gemm_kernel<EP_EMB><<<dim3(M / 64, 512 / 64), 256, 0, stream>>>(
        x, emb_w, emb_b, nullptr, h0, M, 512, 512);

    // 2) Q/K/V projections
    gemm_kernel<EP_NONE><<<dim3(M / 64, 512 / 64), 256, 0, stream>>>(
        h0, Wqr, nullptr, nullptr, Q, M, 512, 512);
    gemm_kernel<EP_NONE><<<dim3(M / 64, 512 / 64), 256, 0, stream>>>(
        h0, Wkr, nullptr, nullptr, Kb, M, 512, 512);
    gemm_kernel<EP_NONE><<<dim3(M / 64, 512 / 64), 256, 0, stream>>>(
        h0, Wvr, nullptr, nullptr, V, M, 512, 512);

    // 3) fused attention -> headR ([B,H,S,DK] flat == raw reshape [B,S,512])
    attn_kernel<<<dim3(128, 4, 16), 256, 0, stream>>>(Q, Kb, V, headR);

    // 4) r1 = headR @ WO + h0 ; ln1 = LN(r1)
    gemm_kernel<EP_RES><<<dim3(M / 64, 512 / 64), 256, 0, stream>>>(
        headR, WO, nullptr, h0, r1, M, 512, 512);
    ln_kernel<<<M, 256, 0, stream>>>(r1, g1, b1, ln1);

    // 5) FFN
    gemm_kernel<EP_BIAS_RELU><<<dim3(M / 64, 2048 / 64), 256, 0, stream>>>(
        ln1, l1w, l1b, nullptr, mid, M, 2048, 512);
    gemm_kernel<EP_BIAS_RES><<<dim3(M / 64, 512 / 64), 256, 0, stream>>>(
        mid, l2w, l2b, ln1, r2, M, 512, 2048);
    ln_kernel<<<M, 256, 0, stream>>>(r2, g2, b2, ln2);

    // 6) maxpool + FC + log_softmax
    final_kernel<<<16, 256, 0, stream>>>(ln2, fcw, fcb, out);
}

// Round 4
// 1850.694 us; speedup vs baseline: 2.6989x; 2.6989x over previous
//
#include <hip/hip_runtime.h>

typedef unsigned short ushortb;
typedef __attribute__((ext_vector_type(8))) short short8;    // 8 bf16 = 16B (MFMA A/B frag)
typedef __attribute__((ext_vector_type(4))) float f32x4;     // MFMA C/D frag

__device__ __forceinline__ ushortb f2bb(float f) {
    union { float f; unsigned u; } x; x.f = f;
    unsigned r = x.u + 0x7fffu + ((x.u >> 16) & 1u);   // RNE
    return (ushortb)(r >> 16);
}

// ---------------------------------------------------------------------------
// Epilogue modes for the generic tiled GEMM
#define EP_EMB       0   // + bias + positional encoding (fp32 out)
#define EP_NONE      1   // plain fp32 store
#define EP_RES       2   // + residual (fp32 out)
#define EP_BIAS_RELU 3   // + bias, relu (fp32 out)
#define EP_BIAS_RES  4   // + bias + residual (fp32 out)
#define EP_BF16      5   // store bf16 * scale to Cb [M,N]
#define EP_VT        6   // store bf16 transposed: Vt[(b*4+h)*128+e][s]

// C[M,N] = A[M,K] @ B[K,N] (+ epilogue). fp32 row-major, fp32 accum.
// 64x64 tile, 256 threads, 4x4 micro-tile per thread, K-tile 16.
template <int EP>
__global__ __launch_bounds__(256) void gemm_kernel(
    const float* __restrict__ A, const float* __restrict__ B,
    const float* __restrict__ bias, const float* __restrict__ res,
    float* __restrict__ C, ushortb* __restrict__ Cb, float scale,
    int M, int N, int K)
{
    __shared__ float As[16][68];
    __shared__ float Bs[16][68];
    const int tid = threadIdx.x;
    const int row0 = blockIdx.x * 64;
    const int col0 = blockIdx.y * 64;
    const int ty = tid >> 4, tx = tid & 15;

    float acc[4][4] = {};

    for (int k0 = 0; k0 < K; k0 += 16) {
        #pragma unroll
        for (int l = 0; l < 4; ++l) {
            int e = tid + l * 256;
            int m = e >> 4, kk = e & 15;
            As[kk][m] = A[(size_t)(row0 + m) * K + k0 + kk];
        }
        #pragma unroll
        for (int l = 0; l < 4; ++l) {
            int e = tid + l * 256;
            int kk = e >> 6, n = e & 63;
            Bs[kk][n] = B[(size_t)(k0 + kk) * N + col0 + n];
        }
        __syncthreads();
        #pragma unroll
        for (int kk = 0; kk < 16; ++kk) {
            float4 a4 = *(const float4*)&As[kk][ty * 4];
            float4 b4 = *(const float4*)&Bs[kk][tx * 4];
            float a[4] = {a4.x, a4.y, a4.z, a4.w};
            float b[4] = {b4.x, b4.y, b4.z, b4.w};
            #pragma unroll
            for (int i = 0; i < 4; ++i)
                #pragma unroll
                for (int j = 0; j < 4; ++j)
                    acc[i][j] += a[i] * b[j];
        }
        __syncthreads();
    }

    if constexpr (EP == EP_VT) {
        // row = b*1024 + s, col = h*128 + e  ->  Vt[(b*4+h)*128+e][s]
        int bb = row0 >> 10;
        int s0 = (row0 & 1023) + ty * 4;
        #pragma unroll
        for (int j = 0; j < 4; ++j) {
            int col = col0 + tx * 4 + j;
            int h = col >> 7, e = col & 127;
            ushort4 v;
            v.x = f2bb(acc[0][j]); v.y = f2bb(acc[1][j]);
            v.z = f2bb(acc[2][j]); v.w = f2bb(acc[3][j]);
            *(ushort4*)&Cb[((size_t)((bb * 4 + h) * 128 + e) << 10) + s0] = v;
        }
        return;
    }

    #pragma unroll
    for (int i = 0; i < 4; ++i) {
        int row = row0 + ty * 4 + i;
        #pragma unroll
        for (int j = 0; j < 4; ++j) {
            int col = col0 + tx * 4 + j;
            float v = acc[i][j];
            if constexpr (EP == EP_EMB) {
                v += bias[col];
                int s = row & 1023;
                float div = expf((float)(col & ~1) * (-9.210340371976184f / 512.0f));
                float ang = (float)s * div;
                v += (col & 1) ? cosf(ang) : sinf(ang);
            } else if constexpr (EP == EP_RES) {
                v += res[(size_t)row * N + col];
            } else if constexpr (EP == EP_BIAS_RELU) {
                v += bias[col];
                v = fmaxf(v, 0.0f);
            } else if constexpr (EP == EP_BIAS_RES) {
                v += bias[col] + res[(size_t)row * N + col];
            }
            if constexpr (EP == EP_BF16) {
                Cb[(size_t)row * N + col] = f2bb(v * scale);
            } else {
                C[(size_t)row * N + col] = v;
            }
        }
    }
}

// ---------------------------------------------------------------------------
// Repack W[H,D,DK] -> Wr[D, H*DK]
__global__ __launch_bounds__(256) void repack_kernel(const float* __restrict__ W,
                                                     float* __restrict__ Wr)
{
    int idx = blockIdx.x * 256 + threadIdx.x;
    int k = idx >> 9;
    int he = idx & 511;
    int h = he >> 7, e = he & 127;
    Wr[idx] = W[(size_t)(h * 512 + k) * 128 + e];
}

// ---------------------------------------------------------------------------
// MFMA flash attention. Inputs: Qb (bf16, pre-scaled by 1/sqrt(128), [B*S,512],
// head offset h*128), Kb (bf16, same layout), Vt (bf16 transposed [64][128][1024]).
// Output O fp32 in [B,H,S,DK] flat layout (== reference raw reshape).
// Block: 256 thr (4 waves), grid (16 q-chunks, 4 heads, 16 batch).
// Wave w owns 16 q rows; t streamed in tiles of 32.
__global__ __launch_bounds__(256) void attn_mfma(
    const ushortb* __restrict__ Qb, const ushortb* __restrict__ Kb,
    const ushortb* __restrict__ Vt, float* __restrict__ O)
{
    __shared__ ushortb sK[32][136];     // [t][d]  (rows 272B = 17x16B, 16B-aligned)
    __shared__ ushortb sVt[128][40];    // [d][t]  (rows 80B = 5x16B, 16B-aligned)
    __shared__ ushortb sP[4][16][40];   // per-wave P tile [q][t]

    const int tid = threadIdx.x;
    const int wave = tid >> 6, lane = tid & 63;
    const int quad = lane >> 4, l15 = lane & 15;
    const int b = blockIdx.z, h = blockIdx.y;
    const int q0 = blockIdx.x * 64 + wave * 16;
    const size_t qk_off = ((size_t)b << 10) * 512 + h * 128;
    const ushortb* Qp = Qb + qk_off;
    const ushortb* Kp = Kb + qk_off;
    const ushortb* Vp = Vt + (((size_t)(b * 4 + h)) << 17);   // 128*1024

    // Q fragments in registers: lane holds Q[q0+l15][kc*32 + quad*8 + j]
    short8 qfrag[4];
    {
        const ushortb* qrow = Qp + (size_t)(q0 + l15) * 512;
        #pragma unroll
        for (int kc = 0; kc < 4; ++kc)
            qfrag[kc] = *(const short8*)(qrow + kc * 32 + quad * 8);
    }

    f32x4 oacc[8];
    #pragma unroll
    for (int dt = 0; dt < 8; ++dt) oacc[dt] = (f32x4){0.f, 0.f, 0.f, 0.f};
    float m_old[4] = {-3.0e38f, -3.0e38f, -3.0e38f, -3.0e38f};
    float l_sum[4] = {0.f, 0.f, 0.f, 0.f};

    for (int t0 = 0; t0 < 1024; t0 += 32) {
        __syncthreads();   // previous tile fully consumed
        // stage K tile [32][128]
        #pragma unroll
        for (int c = 0; c < 2; ++c) {
            int idx = c * 2048 + tid * 8;
            int t = idx >> 7, d0 = idx & 127;
            *(short8*)&sK[t][d0] = *(const short8*)(Kp + (size_t)(t0 + t) * 512 + d0);
        }
        // stage V^T tile [128 d][32 t] from Vt rows (contiguous in t)
        #pragma unroll
        for (int c = 0; c < 2; ++c) {
            int idx = c * 256 + tid;          // 0..511 vectors of 8
            int d = idx >> 2, toff = (idx & 3) * 8;
            *(short8*)&sVt[d][toff] = *(const short8*)(Vp + ((size_t)d << 10) + t0 + toff);
        }
        __syncthreads();

        // QK^T: 16q x 32t scores
        f32x4 sacc0 = {0.f, 0.f, 0.f, 0.f}, sacc1 = {0.f, 0.f, 0.f, 0.f};
        #pragma unroll
        for (int kc = 0; kc < 4; ++kc) {
            short8 b0 = *(const short8*)&sK[l15][kc * 32 + quad * 8];
            short8 b1 = *(const short8*)&sK[16 + l15][kc * 32 + quad * 8];
            sacc0 = __builtin_amdgcn_mfma_f32_16x16x32_bf16(qfrag[kc], b0, sacc0, 0, 0, 0);
            sacc1 = __builtin_amdgcn_mfma_f32_16x16x32_bf16(qfrag[kc], b1, sacc1, 0, 0, 0);
        }
        // C layout: row q = quad*4+reg, col t = t0 + (l15 | l15+16)

        // online softmax per row
        float alpha[4];
        #pragma unroll
        for (int r = 0; r < 4; ++r) {
            float v = fmaxf(sacc0[r], sacc1[r]);
            v = fmaxf(v, __shfl_xor(v, 1));
            v = fmaxf(v, __shfl_xor(v, 2));
            v = fmaxf(v, __shfl_xor(v, 4));
            v = fmaxf(v, __shfl_xor(v, 8));
            float mnew = fmaxf(m_old[r], v);
            alpha[r] = __expf(m_old[r] - mnew);
            float p0 = __expf(sacc0[r] - mnew);
            float p1 = __expf(sacc1[r] - mnew);
            m_old[r] = mnew;
            sP[wave][quad * 4 + r][l15]      = f2bb(p0);
            sP[wave][quad * 4 + r][16 + l15] = f2bb(p1);
            float s = p0 + p1;
            s += __shfl_xor(s, 1);
            s += __shfl_xor(s, 2);
            s += __shfl_xor(s, 4);
            s += __shfl_xor(s, 8);
            l_sum[r] = l_sum[r] * alpha[r] + s;
        }

        // rescale O accumulator
        #pragma unroll
        for (int dt = 0; dt < 8; ++dt)
            #pragma unroll
            for (int r = 0; r < 4; ++r) oacc[dt][r] *= alpha[r];

        // P fragment (A-layout): lane holds P[l15][quad*8 + j]  (same-wave LDS RT)
        short8 pfrag = *(const short8*)&sP[wave][l15][quad * 8];

        // PV: one 16x16x32 MFMA per 16-wide d tile
        #pragma unroll
        for (int dt = 0; dt < 8; ++dt) {
            short8 vfrag = *(const short8*)&sVt[dt * 16 + l15][quad * 8];
            oacc[dt] = __builtin_amdgcn_mfma_f32_16x16x32_bf16(pfrag, vfrag, oacc[dt], 0, 0, 0);
        }
    }

    // epilogue: O / l, store to [B,H,S,DK] flat
    const size_t obase = (((size_t)(b * 4 + h) << 10) + q0) << 7;
    #pragma unroll
    for (int r = 0; r < 4; ++r) {
        float invl = 1.0f / l_sum[r];
        int q = quad * 4 + r;
        #pragma unroll
        for (int dt = 0; dt < 8; ++dt)
            O[obase + ((size_t)q << 7) + dt * 16 + l15] = oacc[dt][r] * invl;
    }
}

// ---------------------------------------------------------------------------
__global__ __launch_bounds__(256) void ln_kernel(const float* __restrict__ in,
                                                 const float* __restrict__ g,
                                                 const float* __restrict__ bta,
                                                 float* __restrict__ out)
{
    const size_t row = blockIdx.x;
    const int tid = threadIdx.x;
    float v0 = in[row * 512 + tid];
    float v1 = in[row * 512 + 256 + tid];
    __shared__ float ss[256], sq[256];
    ss[tid] = v0 + v1;
    sq[tid] = v0 * v0 + v1 * v1;
    __syncthreads();
    for (int o = 128; o > 0; o >>= 1) {
        if (tid < o) { ss[tid] += ss[tid + o]; sq[tid] += sq[tid + o]; }
        __syncthreads();
    }
    float mu = ss[0] * (1.0f / 512.0f);
    float var = sq[0] * (1.0f / 512.0f) - mu * mu;
    float rstd = rsqrtf(var + 1e-5f);
    out[row * 512 + tid]       = (v0 - mu) * rstd * g[tid] + bta[tid];
    out[row * 512 + 256 + tid] = (v1 - mu) * rstd * g[tid + 256] + bta[tid + 256];
}

// ---------------------------------------------------------------------------
__global__ __launch_bounds__(256) void final_kernel(const float* __restrict__ ln2,
                                                    const float* __restrict__ fcw,
                                                    const float* __restrict__ fcb,
                                                    float* __restrict__ out)
{
    const int b = blockIdx.x;
    const int tid = threadIdx.x;
    float a0 = 0.0f, a1 = 0.0f;
    for (int m = tid; m < 32768; m += 256) {
        int s = m >> 5, j = m & 31;
        const float* p = ln2 + ((size_t)(b * 1024 + s) * 512) + j * 16;
        float mx = -1e30f;
        #pragma unroll
        for (int t = 0; t < 16; ++t) mx = fmaxf(mx, p[t]);
        a0 += mx * fcw[2 * m];
        a1 += mx * fcw[2 * m + 1];
    }
    __shared__ float r0[256], r1[256];
    r0[tid] = a0; r1[tid] = a1;
    __syncthreads();
    for (int o = 128; o > 0; o >>= 1) {
        if (tid < o) { r0[tid] += r0[tid + o]; r1[tid] += r1[tid + o]; }
        __syncthreads();
    }
    if (tid == 0) {
        float z0 = r0[0] + fcb[0];
        float z1 = r1[0] + fcb[1];
        float mx = fmaxf(z0, z1);
        float lse = mx + logf(expf(z0 - mx) + expf(z1 - mx));
        out[b * 2 + 0] = z0 - lse;
        out[b * 2 + 1] = z1 - lse;
    }
}

// ---------------------------------------------------------------------------
extern "C" void kernel_launch(void* const* d_in, const int* in_sizes, int n_in,
                              void* d_out, int out_size, void* d_ws, size_t ws_size,
                              hipStream_t stream)
{
    const float* x     = (const float*)d_in[0];
    const float* emb_w = (const float*)d_in[1];
    const float* emb_b = (const float*)d_in[2];
    const float* WQ    = (const float*)d_in[3];
    const float* WK    = (const float*)d_in[4];
    const float* WV    = (const float*)d_in[5];
    const float* WO    = (const float*)d_in[6];
    const float* g1    = (const float*)d_in[7];
    const float* b1    = (const float*)d_in[8];
    const float* l1w   = (const float*)d_in[9];
    const float* l1b   = (const float*)d_in[10];
    const float* l2w   = (const float*)d_in[11];
    const float* l2b   = (const float*)d_in[12];
    const float* g2    = (const float*)d_in[13];
    const float* b2    = (const float*)d_in[14];
    const float* fcw   = (const float*)d_in[15];
    const float* fcb   = (const float*)d_in[16];
    float* out = (float*)d_out;

    char* ws = (char*)d_ws;
    const size_t U = (size_t)16384 * 512 * 4;     // 33.55 MB fp32 unit; total 6U = 201.3 MB
    // u0: Qb+Kb (bf16) -> ln1 -> ln2     u1: Vt (bf16) -> r1 -> r2
    // u2: headR -> mid[0]                u3: Wq/Wk/Wv repack -> mid[1]
    // u4: mid[2]                         u5: h0 -> mid[3]
    ushortb* Qb  = (ushortb*)(ws + 0 * U);
    ushortb* Kb2 = (ushortb*)(ws + 0 * U + U / 2);
    ushortb* Vt  = (ushortb*)(ws + 1 * U);
    float* headR = (float*)(ws + 2 * U);
    float* h0    = (float*)(ws + 5 * U);
    float* mid   = (float*)(ws + 2 * U);
    float* r1    = (float*)(ws + 1 * U);
    float* ln1   = (float*)(ws + 0 * U);
    float* r2    = (float*)(ws + 1 * U);
    float* ln2   = (float*)(ws + 0 * U);
    float* Wqr   = (float*)(ws + 3 * U);
    float* Wkr   = (float*)(ws + 3 * U + (size_t)512 * 512 * 4);
    float* Wvr   = (float*)(ws + 3 * U + (size_t)2 * 512 * 512 * 4);

    const int M = 16384;

    repack_kernel<<<1024, 256, 0, stream>>>(WQ, Wqr);
    repack_kernel<<<1024, 256, 0, stream>>>(WK, Wkr);
    repack_kernel<<<1024, 256, 0, stream>>>(WV, Wvr);

    // 1) h0 = x @ emb_w + emb_b + pos_encoding  (fp32)
    gemm_kernel<EP_EMB><<<dim3(M / 64, 8), 256, 0, stream>>>(
        x, emb_w, emb_b, nullptr, h0, nullptr, 1.0f, M, 512, 512);

    // 2) Q/K/V projections: Q bf16 pre-scaled 1/sqrt(128); K bf16; V bf16 transposed
    gemm_kernel<EP_BF16><<<dim3(M / 64, 8), 256, 0, stream>>>(
        h0, Wqr, nullptr, nullptr, nullptr, Qb, 0.08838834764831845f, M, 512, 512);
    gemm_kernel<EP_BF16><<<dim3(M / 64, 8), 256, 0, stream>>>(
        h0, Wkr, nullptr, nullptr, nullptr, Kb2, 1.0f, M, 512, 512);
    gemm_kernel<EP_VT><<<dim3(M / 64, 8), 256, 0, stream>>>(
        h0, Wvr, nullptr, nullptr, nullptr, Vt, 1.0f, M, 512, 512);

    // 3) MFMA flash attention -> headR fp32 ([B,H,S,DK] flat == raw reshape)
    attn_mfma<<<dim3(16, 4, 16), 256, 0, stream>>>(Qb, Kb2, Vt, headR);

    // 4) r1 = headR @ WO + h0 ; ln1 = LN(r1)
    gemm_kernel<EP_RES><<<dim3(M / 64, 8), 256, 0, stream>>>(
        headR, WO, nullptr, h0, r1, nullptr, 1.0f, M, 512, 512);
    ln_kernel<<<M, 256, 0, stream>>>(r1, g1, b1, ln1);

    // 5) FFN
    gemm_kernel<EP_BIAS_RELU><<<dim3(M / 64, 32), 256, 0, stream>>>(
        ln1, l1w, l1b, nullptr, mid, nullptr, 1.0f, M, 2048, 512);
    gemm_kernel<EP_BIAS_RES><<<dim3(M / 64, 8), 256, 0, stream>>>(
        mid, l2w, l2b, ln1, r2, nullptr, 1.0f, M, 512, 2048);
    ln_kernel<<<M, 256, 0, stream>>>(r2, g2, b2, ln2);

    // 6) maxpool + FC + log_softmax
    final_kernel<<<16, 256, 0, stream>>>(ln2, fcw, fcb, out);
}

// Round 6
// 550.804 us; speedup vs baseline: 9.0684x; 3.3600x over previous
//
#include <hip/hip_runtime.h>

typedef unsigned short ushortb;
typedef __attribute__((ext_vector_type(8))) short short8;    // 8 bf16 = 16B (MFMA A/B frag)
typedef __attribute__((ext_vector_type(4))) float f32x4;     // MFMA C/D frag

__device__ __forceinline__ ushortb f2bb(float f) {
    union { float f; unsigned u; } x; x.f = f;
    unsigned r = x.u + 0x7fffu + ((x.u >> 16) & 1u);   // RNE
    return (ushortb)(r >> 16);
}
__device__ __forceinline__ float bb2f(ushortb u) {
    union { unsigned u; float f; } x; x.u = ((unsigned)u) << 16; return x.f;
}

// ---------------------------------------------------------------------------
// Epilogue modes
#define EP_EMB       0   // + bias + pe table
#define EP_NONE      1   // plain bf16 store
#define EP_RES       2   // + bf16 residual
#define EP_BIAS_RELU 3   // + bias, relu
#define EP_BIAS_RES  4   // + bias + bf16 residual
#define EP_VT        6   // store transposed: Vt[(b*4+h)*128+e][s]

// C[M,N] = A[M,K] @ Bt[N,K]^T (+ epilogue). bf16 in, fp32 MFMA accum, bf16 out.
// Block 256 thr (4 waves, 2x2), tile 128x128, BK=32.
// Wave computes 64x64 = 4x4 grid of 16x16x32 MFMA.
template <int EP>
__global__ __launch_bounds__(256) void gemm_mfma(
    const ushortb* __restrict__ A, const ushortb* __restrict__ Bt,
    const float* __restrict__ bias, const ushortb* __restrict__ res,
    const float* __restrict__ pe, ushortb* __restrict__ C,
    int M, int N, int K)
{
    __shared__ ushortb sA[128][40];   // [m][k] rows 80B (=5x16B) -> 2-way banks, free
    __shared__ ushortb sB[128][40];   // [n][k]

    const int tid = threadIdx.x;
    const int wave = tid >> 6, lane = tid & 63;
    const int quad = lane >> 4, l15 = lane & 15;
    const int row0 = blockIdx.x * 128;
    const int col0 = blockIdx.y * 128;
    const int wm = (wave >> 1) * 64, wn = (wave & 1) * 64;

    f32x4 acc[4][4];
    #pragma unroll
    for (int i = 0; i < 4; ++i)
        #pragma unroll
        for (int j = 0; j < 4; ++j) acc[i][j] = (f32x4){0.f, 0.f, 0.f, 0.f};

    for (int k0 = 0; k0 < K; k0 += 32) {
        __syncthreads();
        // stage A tile [128][32] and B tile [128][32] (512 short8 vectors each)
        #pragma unroll
        for (int c = 0; c < 2; ++c) {
            int idx = c * 256 + tid;
            int r = idx >> 2, c8 = (idx & 3) * 8;
            *(short8*)&sA[r][c8] = *(const short8*)(A + (size_t)(row0 + r) * K + k0 + c8);
            *(short8*)&sB[r][c8] = *(const short8*)(Bt + (size_t)(col0 + r) * K + k0 + c8);
        }
        __syncthreads();

        short8 af[4], bf[4];
        #pragma unroll
        for (int i = 0; i < 4; ++i)
            af[i] = *(const short8*)&sA[wm + i * 16 + l15][quad * 8];
        #pragma unroll
        for (int j = 0; j < 4; ++j)
            bf[j] = *(const short8*)&sB[wn + j * 16 + l15][quad * 8];
        #pragma unroll
        for (int i = 0; i < 4; ++i)
            #pragma unroll
            for (int j = 0; j < 4; ++j)
                acc[i][j] = __builtin_amdgcn_mfma_f32_16x16x32_bf16(af[i], bf[j], acc[i][j], 0, 0, 0);
    }

    if constexpr (EP == EP_VT) {
        // row = b*1024 + s, col = h*128 + e  ->  Vt[(b*4+h)*128+e][s] (8B stores)
        int bb = row0 >> 10;
        #pragma unroll
        for (int i = 0; i < 4; ++i) {
            int s = (row0 & 1023) + wm + i * 16 + quad * 4;
            #pragma unroll
            for (int j = 0; j < 4; ++j) {
                int col = col0 + wn + j * 16 + l15;
                int h = col >> 7, e = col & 127;
                ushort4 v;
                v.x = f2bb(acc[i][j][0]); v.y = f2bb(acc[i][j][1]);
                v.z = f2bb(acc[i][j][2]); v.w = f2bb(acc[i][j][3]);
                *(ushort4*)&C[((size_t)((bb * 4 + h) * 128 + e) << 10) + s] = v;
            }
        }
        return;
    }

    #pragma unroll
    for (int i = 0; i < 4; ++i) {
        #pragma unroll
        for (int r = 0; r < 4; ++r) {
            int row = row0 + wm + i * 16 + quad * 4 + r;
            #pragma unroll
            for (int j = 0; j < 4; ++j) {
                int col = col0 + wn + j * 16 + l15;
                float v = acc[i][j][r];
                if constexpr (EP == EP_EMB) {
                    v += bias[col] + pe[((row & 1023) << 9) + col];
                } else if constexpr (EP == EP_RES) {
                    v += bb2f(res[(size_t)row * N + col]);
                } else if constexpr (EP == EP_BIAS_RELU) {
                    v = fmaxf(v + bias[col], 0.0f);
                } else if constexpr (EP == EP_BIAS_RES) {
                    v += bias[col] + bb2f(res[(size_t)row * N + col]);
                }
                C[(size_t)row * N + col] = f2bb(v);
            }
        }
    }
}

// ---------------------------------------------------------------------------
// Prep kernels
// x fp32 -> bf16, 4 elems/thread
__global__ __launch_bounds__(256) void conv_x(const float* __restrict__ in,
                                              ushortb* __restrict__ out)
{
    size_t i4 = (size_t)blockIdx.x * 256 + threadIdx.x;
    float4 v = *(const float4*)(in + i4 * 4);
    ushort4 o;
    o.x = f2bb(v.x); o.y = f2bb(v.y); o.z = f2bb(v.z); o.w = f2bb(v.w);
    *(ushort4*)(out + i4 * 4) = o;
}

// W fp32 [K][N] -> bf16 Wt [N][K]
__global__ __launch_bounds__(256) void conv_t(const float* __restrict__ W,
                                              ushortb* __restrict__ Wt, int N, int K)
{
    int idx = blockIdx.x * 256 + threadIdx.x;    // n*K + k
    int n = idx / K, k = idx - n * K;
    Wt[idx] = f2bb(W[(size_t)k * N + n]);
}

// W fp32 [H=4][D=512][DK=128] -> bf16 Wt[n=h*128+e][k=d], * scale
__global__ __launch_bounds__(256) void repack_t(const float* __restrict__ W,
                                                ushortb* __restrict__ Wt, float scale)
{
    int idx = blockIdx.x * 256 + threadIdx.x;    // n*512 + k
    int n = idx >> 9, k = idx & 511;
    int h = n >> 7, e = n & 127;
    Wt[idx] = f2bb(W[(size_t)(h * 512 + k) * 128 + e] * scale);
}

// positional encoding table fp32 [1024][512]
__global__ __launch_bounds__(256) void pe_kernel(float* __restrict__ pe)
{
    int idx = blockIdx.x * 256 + threadIdx.x;    // s*512 + c
    int s = idx >> 9, c = idx & 511;
    float div = expf((float)(c & ~1) * (-9.210340371976184f / 512.0f));
    float ang = (float)s * div;
    pe[idx] = (c & 1) ? cosf(ang) : sinf(ang);
}

// ---------------------------------------------------------------------------
// MFMA flash attention (verified R4). Qb pre-scaled bf16 [B*S,512] (+h*128),
// Kb bf16 same, Vt bf16 [(b*4+h)*128+e][1024]. O bf16 [B,H,S,DK] flat.
__global__ __launch_bounds__(256) void attn_mfma(
    const ushortb* __restrict__ Qb, const ushortb* __restrict__ Kb,
    const ushortb* __restrict__ Vt, ushortb* __restrict__ O)
{
    __shared__ ushortb sK[32][136];
    __shared__ ushortb sVt[128][40];
    __shared__ ushortb sP[4][16][40];

    const int tid = threadIdx.x;
    const int wave = tid >> 6, lane = tid & 63;
    const int quad = lane >> 4, l15 = lane & 15;
    const int b = blockIdx.z, h = blockIdx.y;
    const int q0 = blockIdx.x * 64 + wave * 16;
    const size_t qk_off = ((size_t)b << 10) * 512 + h * 128;
    const ushortb* Qp = Qb + qk_off;
    const ushortb* Kp = Kb + qk_off;
    const ushortb* Vp = Vt + (((size_t)(b * 4 + h)) << 17);

    short8 qfrag[4];
    {
        const ushortb* qrow = Qp + (size_t)(q0 + l15) * 512;
        #pragma unroll
        for (int kc = 0; kc < 4; ++kc)
            qfrag[kc] = *(const short8*)(qrow + kc * 32 + quad * 8);
    }

    f32x4 oacc[8];
    #pragma unroll
    for (int dt = 0; dt < 8; ++dt) oacc[dt] = (f32x4){0.f, 0.f, 0.f, 0.f};
    float m_old[4] = {-3.0e38f, -3.0e38f, -3.0e38f, -3.0e38f};
    float l_sum[4] = {0.f, 0.f, 0.f, 0.f};

    for (int t0 = 0; t0 < 1024; t0 += 32) {
        __syncthreads();
        #pragma unroll
        for (int c = 0; c < 2; ++c) {
            int idx = c * 2048 + tid * 8;
            int t = idx >> 7, d0 = idx & 127;
            *(short8*)&sK[t][d0] = *(const short8*)(Kp + (size_t)(t0 + t) * 512 + d0);
        }
        #pragma unroll
        for (int c = 0; c < 2; ++c) {
            int idx = c * 256 + tid;
            int d = idx >> 2, toff = (idx & 3) * 8;
            *(short8*)&sVt[d][toff] = *(const short8*)(Vp + ((size_t)d << 10) + t0 + toff);
        }
        __syncthreads();

        f32x4 sacc0 = {0.f, 0.f, 0.f, 0.f}, sacc1 = {0.f, 0.f, 0.f, 0.f};
        #pragma unroll
        for (int kc = 0; kc < 4; ++kc) {
            short8 b0 = *(const short8*)&sK[l15][kc * 32 + quad * 8];
            short8 b1 = *(const short8*)&sK[16 + l15][kc * 32 + quad * 8];
            sacc0 = __builtin_amdgcn_mfma_f32_16x16x32_bf16(qfrag[kc], b0, sacc0, 0, 0, 0);
            sacc1 = __builtin_amdgcn_mfma_f32_16x16x32_bf16(qfrag[kc], b1, sacc1, 0, 0, 0);
        }

        float alpha[4];
        #pragma unroll
        for (int r = 0; r < 4; ++r) {
            float v = fmaxf(sacc0[r], sacc1[r]);
            v = fmaxf(v, __shfl_xor(v, 1));
            v = fmaxf(v, __shfl_xor(v, 2));
            v = fmaxf(v, __shfl_xor(v, 4));
            v = fmaxf(v, __shfl_xor(v, 8));
            float mnew = fmaxf(m_old[r], v);
            alpha[r] = __expf(m_old[r] - mnew);
            float p0 = __expf(sacc0[r] - mnew);
            float p1 = __expf(sacc1[r] - mnew);
            m_old[r] = mnew;
            sP[wave][quad * 4 + r][l15]      = f2bb(p0);
            sP[wave][quad * 4 + r][16 + l15] = f2bb(p1);
            float s = p0 + p1;
            s += __shfl_xor(s, 1);
            s += __shfl_xor(s, 2);
            s += __shfl_xor(s, 4);
            s += __shfl_xor(s, 8);
            l_sum[r] = l_sum[r] * alpha[r] + s;
        }

        #pragma unroll
        for (int dt = 0; dt < 8; ++dt)
            #pragma unroll
            for (int r = 0; r < 4; ++r) oacc[dt][r] *= alpha[r];

        short8 pfrag = *(const short8*)&sP[wave][l15][quad * 8];

        #pragma unroll
        for (int dt = 0; dt < 8; ++dt) {
            short8 vfrag = *(const short8*)&sVt[dt * 16 + l15][quad * 8];
            oacc[dt] = __builtin_amdgcn_mfma_f32_16x16x32_bf16(pfrag, vfrag, oacc[dt], 0, 0, 0);
        }
    }

    const size_t obase = (((size_t)(b * 4 + h) << 10) + q0) << 7;
    #pragma unroll
    for (int r = 0; r < 4; ++r) {
        float invl = 1.0f / l_sum[r];
        int q = quad * 4 + r;
        #pragma unroll
        for (int dt = 0; dt < 8; ++dt)
            O[obase + ((size_t)q << 7) + dt * 16 + l15] = f2bb(oacc[dt][r] * invl);
    }
}

// ---------------------------------------------------------------------------
// LayerNorm over 512 features, bf16 in/out, fp32 gamma/beta & math.
__global__ __launch_bounds__(256) void ln_kernel(const ushortb* __restrict__ in,
                                                 const float* __restrict__ g,
                                                 const float* __restrict__ bta,
                                                 ushortb* __restrict__ out)
{
    const size_t row = blockIdx.x;
    const int tid = threadIdx.x;
    float v0 = bb2f(in[row * 512 + tid]);
    float v1 = bb2f(in[row * 512 + 256 + tid]);
    __shared__ float ss[256], sq[256];
    ss[tid] = v0 + v1;
    sq[tid] = v0 * v0 + v1 * v1;
    __syncthreads();
    for (int o = 128; o > 0; o >>= 1) {
        if (tid < o) { ss[tid] += ss[tid + o]; sq[tid] += sq[tid + o]; }
        __syncthreads();
    }
    float mu = ss[0] * (1.0f / 512.0f);
    float var = sq[0] * (1.0f / 512.0f) - mu * mu;
    float rstd = rsqrtf(var + 1e-5f);
    out[row * 512 + tid]       = f2bb((v0 - mu) * rstd * g[tid] + bta[tid]);
    out[row * 512 + 256 + tid] = f2bb((v1 - mu) * rstd * g[tid + 256] + bta[tid + 256]);
}

// ---------------------------------------------------------------------------
// MaxPool1d(16) + FC[32768,2] + log_softmax. One block per batch.
__global__ __launch_bounds__(256) void final_kernel(const ushortb* __restrict__ ln2,
                                                    const float* __restrict__ fcw,
                                                    const float* __restrict__ fcb,
                                                    float* __restrict__ out)
{
    const int b = blockIdx.x;
    const int tid = threadIdx.x;
    float a0 = 0.0f, a1 = 0.0f;
    for (int m = tid; m < 32768; m += 256) {
        int s = m >> 5, j = m & 31;
        const ushortb* p = ln2 + ((size_t)(b * 1024 + s) * 512) + j * 16;
        float mx = -1e30f;
        #pragma unroll
        for (int t = 0; t < 16; ++t) mx = fmaxf(mx, bb2f(p[t]));
        a0 += mx * fcw[2 * m];
        a1 += mx * fcw[2 * m + 1];
    }
    __shared__ float r0[256], r1[256];
    r0[tid] = a0; r1[tid] = a1;
    __syncthreads();
    for (int o = 128; o > 0; o >>= 1) {
        if (tid < o) { r0[tid] += r0[tid + o]; r1[tid] += r1[tid + o]; }
        __syncthreads();
    }
    if (tid == 0) {
        float z0 = r0[0] + fcb[0];
        float z1 = r1[0] + fcb[1];
        float mx = fmaxf(z0, z1);
        float lse = mx + logf(expf(z0 - mx) + expf(z1 - mx));
        out[b * 2 + 0] = z0 - lse;
        out[b * 2 + 1] = z1 - lse;
    }
}

// ---------------------------------------------------------------------------
extern "C" void kernel_launch(void* const* d_in, const int* in_sizes, int n_in,
                              void* d_out, int out_size, void* d_ws, size_t ws_size,
                              hipStream_t stream)
{
    const float* x     = (const float*)d_in[0];
    const float* emb_w = (const float*)d_in[1];
    const float* emb_b = (const float*)d_in[2];
    const float* WQ    = (const float*)d_in[3];
    const float* WK    = (const float*)d_in[4];
    const float* WV    = (const float*)d_in[5];
    const float* WO    = (const float*)d_in[6];
    const float* g1    = (const float*)d_in[7];
    const float* b1    = (const float*)d_in[8];
    const float* l1w   = (const float*)d_in[9];
    const float* l1b   = (const float*)d_in[10];
    const float* l2w   = (const float*)d_in[11];
    const float* l2b   = (const float*)d_in[12];
    const float* g2    = (const float*)d_in[13];
    const float* b2    = (const float*)d_in[14];
    const float* fcw   = (const float*)d_in[15];
    const float* fcb   = (const float*)d_in[16];
    float* out = (float*)d_out;

    char* ws = (char*)d_ws;
    const size_t Ub = (size_t)16384 * 512 * 2;   // 16.78 MB bf16 activation unit
    // u0: xb -> r1 -> r2       u1: h0b -> ln2     u2: Qb -> ln1
    // u3: Kb -> mid[0]         u4: Vt -> mid[1]   u5: headR -> mid[2]   u6: mid[3]
    ushortb* xb    = (ushortb*)(ws + 0 * Ub);
    ushortb* h0b   = (ushortb*)(ws + 1 * Ub);
    ushortb* Qb    = (ushortb*)(ws + 2 * Ub);
    ushortb* Kb    = (ushortb*)(ws + 3 * Ub);
    ushortb* Vt    = (ushortb*)(ws + 4 * Ub);
    ushortb* headR = (ushortb*)(ws + 5 * Ub);
    ushortb* mid   = (ushortb*)(ws + 3 * Ub);    // [16384,2048] over u3..u6
    ushortb* r1    = xb;
    ushortb* ln1   = Qb;
    ushortb* r2    = xb;
    ushortb* ln2   = h0b;
    char* wb = ws + 7 * Ub;
    ushortb* embwt = (ushortb*)(wb);                       // [512][512]
    ushortb* wqt   = (ushortb*)(wb + 1 * 524288);
    ushortb* wkt   = (ushortb*)(wb + 2 * 524288);
    ushortb* wvt   = (ushortb*)(wb + 3 * 524288);
    ushortb* wot   = (ushortb*)(wb + 4 * 524288);
    ushortb* l1wt  = (ushortb*)(wb + 5 * 524288);          // [2048][512]
    ushortb* l2wt  = (ushortb*)(wb + 9 * 524288);          // [512][2048]
    float*   pe    = (float*)  (wb + 13 * 524288);         // [1024][512] fp32

    const int M = 16384;

    // prep: conversions / transposes / pe table
    conv_x<<<8192, 256, 0, stream>>>(x, xb);
    pe_kernel<<<2048, 256, 0, stream>>>(pe);
    conv_t<<<1024, 256, 0, stream>>>(emb_w, embwt, 512, 512);
    repack_t<<<1024, 256, 0, stream>>>(WQ, wqt, 0.08838834764831845f);
    repack_t<<<1024, 256, 0, stream>>>(WK, wkt, 1.0f);
    repack_t<<<1024, 256, 0, stream>>>(WV, wvt, 1.0f);
    conv_t<<<1024, 256, 0, stream>>>(WO, wot, 512, 512);
    conv_t<<<4096, 256, 0, stream>>>(l1w, l1wt, 2048, 512);
    conv_t<<<4096, 256, 0, stream>>>(l2w, l2wt, 512, 2048);

    // 1) h0 = x @ emb_w + emb_b + pe
    gemm_mfma<EP_EMB><<<dim3(M / 128, 4), 256, 0, stream>>>(
        xb, embwt, emb_b, nullptr, pe, h0b, M, 512, 512);

    // 2) Q/K/V projections (Q scale baked into wqt); V stored transposed
    gemm_mfma<EP_NONE><<<dim3(M / 128, 4), 256, 0, stream>>>(
        h0b, wqt, nullptr, nullptr, nullptr, Qb, M, 512, 512);
    gemm_mfma<EP_NONE><<<dim3(M / 128, 4), 256, 0, stream>>>(
        h0b, wkt, nullptr, nullptr, nullptr, Kb, M, 512, 512);
    gemm_mfma<EP_VT><<<dim3(M / 128, 4), 256, 0, stream>>>(
        h0b, wvt, nullptr, nullptr, nullptr, Vt, M, 512, 512);

    // 3) flash attention -> headR bf16 ([B,H,S,DK] flat == raw reshape)
    attn_mfma<<<dim3(16, 4, 16), 256, 0, stream>>>(Qb, Kb, Vt, headR);

    // 4) r1 = headR @ WO + h0 ; ln1 = LN(r1)
    gemm_mfma<EP_RES><<<dim3(M / 128, 4), 256, 0, stream>>>(
        headR, wot, nullptr, h0b, nullptr, r1, M, 512, 512);
    ln_kernel<<<M, 256, 0, stream>>>(r1, g1, b1, ln1);

    // 5) FFN
    gemm_mfma<EP_BIAS_RELU><<<dim3(M / 128, 16), 256, 0, stream>>>(
        ln1, l1wt, l1b, nullptr, nullptr, mid, M, 2048, 512);
    gemm_mfma<EP_BIAS_RES><<<dim3(M / 128, 4), 256, 0, stream>>>(
        mid, l2wt, l2b, ln1, nullptr, r2, M, 512, 2048);
    ln_kernel<<<M, 256, 0, stream>>>(r2, g2, b2, ln2);

    // 6) maxpool + FC + log_softmax
    final_kernel<<<16, 256, 0, stream>>>(ln2, fcw, fcb, out);
}

// Round 7
// 477.791 us; speedup vs baseline: 10.4541x; 1.1528x over previous
//
#include <hip/hip_runtime.h>

typedef unsigned short ushortb;
typedef __attribute__((ext_vector_type(8))) short short8;    // 8 bf16 = 16B (MFMA A/B frag)
typedef __attribute__((ext_vector_type(4))) float f32x4;     // MFMA C/D frag

__device__ __forceinline__ ushortb f2bb(float f) {
    union { float f; unsigned u; } x; x.f = f;
    unsigned r = x.u + 0x7fffu + ((x.u >> 16) & 1u);   // RNE
    return (ushortb)(r >> 16);
}
__device__ __forceinline__ float bb2f(ushortb u) {
    union { unsigned u; float f; } x; x.u = ((unsigned)u) << 16; return x.f;
}

// async global->LDS DMA, 16B per lane; lds base must be wave-uniform,
// lane's data lands at base + lane*16.
__device__ __forceinline__ void async_ld16(void* lds, const void* g) {
    __builtin_amdgcn_global_load_lds(
        (const __attribute__((address_space(1))) void*)g,
        (__attribute__((address_space(3))) void*)lds, 16, 0, 0);
}

// ---------------------------------------------------------------------------
// Epilogue modes
#define EP_EMB       0   // + bias + pe table
#define EP_NONE      1   // plain bf16 store
#define EP_RES       2   // + bf16 residual
#define EP_BIAS_RELU 3   // + bias, relu
#define EP_BIAS_RES  4   // + bias + bf16 residual
#define EP_VT        6   // store transposed: Vt[(b*4+h)*128+e][s]

// C[M,N] = A[M,K] @ Bt[N,K]^T (+ epilogue). bf16 in, fp32 MFMA accum, bf16 out.
// Block 256 thr (4 waves, 2x2), tile 128x128, BK=32.
// Staging via global_load_lds (16B/lane) into unpadded [128][32] tiles with
// XOR swizzle: LDS slot s of row r holds global 16B-chunk (s ^ sw(r)), where
// sw(r) = (r ^ (r>>2)) & 3 -> fragment reads are <=2-way bank aliased (free).
template <int EP>
__global__ __launch_bounds__(256) void gemm_mfma(
    const ushortb* __restrict__ A, const ushortb* __restrict__ Bt,
    const float* __restrict__ bias, const ushortb* __restrict__ res,
    const float* __restrict__ pe, ushortb* __restrict__ C,
    int M, int N, int K)
{
    __shared__ ushortb sA[128][32];
    __shared__ ushortb sB[128][32];

    const int tid = threadIdx.x;
    const int wave = tid >> 6, lane = tid & 63;
    const int quad = lane >> 4, l15 = lane & 15;
    const int row0 = blockIdx.x * 128;
    const int col0 = blockIdx.y * 128;
    const int wm = (wave >> 1) * 64, wn = (wave & 1) * 64;
    const int srl = lane >> 2, slot = lane & 3;   // staging row-in-call / chunk

    f32x4 acc[4][4];
    #pragma unroll
    for (int i = 0; i < 4; ++i)
        #pragma unroll
        for (int j = 0; j < 4; ++j) acc[i][j] = (f32x4){0.f, 0.f, 0.f, 0.f};

    for (int k0 = 0; k0 < K; k0 += 32) {
        __syncthreads();
        #pragma unroll
        for (int c = 0; c < 2; ++c) {
            int rbase = wave * 32 + c * 16;
            int r = rbase + srl;
            int ka = (slot ^ ((r ^ (r >> 2)) & 3)) * 8;
            async_ld16(&sA[rbase][0], A  + (size_t)(row0 + r) * K + k0 + ka);
            async_ld16(&sB[rbase][0], Bt + (size_t)(col0 + r) * K + k0 + ka);
        }
        __syncthreads();   // drains vmcnt -> tiles resident

        short8 af[4], bf[4];
        #pragma unroll
        for (int i = 0; i < 4; ++i) {
            int m = wm + i * 16 + l15;
            af[i] = *(const short8*)&sA[m][(quad ^ ((m ^ (m >> 2)) & 3)) * 8];
        }
        #pragma unroll
        for (int j = 0; j < 4; ++j) {
            int n = wn + j * 16 + l15;
            bf[j] = *(const short8*)&sB[n][(quad ^ ((n ^ (n >> 2)) & 3)) * 8];
        }
        #pragma unroll
        for (int i = 0; i < 4; ++i)
            #pragma unroll
            for (int j = 0; j < 4; ++j)
                acc[i][j] = __builtin_amdgcn_mfma_f32_16x16x32_bf16(af[i], bf[j], acc[i][j], 0, 0, 0);
    }

    if constexpr (EP == EP_VT) {
        // row = b*1024 + s, col = h*128 + e  ->  Vt[(b*4+h)*128+e][s] (8B stores)
        int bb = row0 >> 10;
        #pragma unroll
        for (int i = 0; i < 4; ++i) {
            int s = (row0 & 1023) + wm + i * 16 + quad * 4;
            #pragma unroll
            for (int j = 0; j < 4; ++j) {
                int col = col0 + wn + j * 16 + l15;
                int h = col >> 7, e = col & 127;
                ushort4 v;
                v.x = f2bb(acc[i][j][0]); v.y = f2bb(acc[i][j][1]);
                v.z = f2bb(acc[i][j][2]); v.w = f2bb(acc[i][j][3]);
                *(ushort4*)&C[((size_t)((bb * 4 + h) * 128 + e) << 10) + s] = v;
            }
        }
        return;
    }

    #pragma unroll
    for (int i = 0; i < 4; ++i) {
        #pragma unroll
        for (int r = 0; r < 4; ++r) {
            int row = row0 + wm + i * 16 + quad * 4 + r;
            #pragma unroll
            for (int j = 0; j < 4; ++j) {
                int col = col0 + wn + j * 16 + l15;
                float v = acc[i][j][r];
                if constexpr (EP == EP_EMB) {
                    v += bias[col] + pe[((row & 1023) << 9) + col];
                } else if constexpr (EP == EP_RES) {
                    v += bb2f(res[(size_t)row * N + col]);
                } else if constexpr (EP == EP_BIAS_RELU) {
                    v = fmaxf(v + bias[col], 0.0f);
                } else if constexpr (EP == EP_BIAS_RES) {
                    v += bias[col] + bb2f(res[(size_t)row * N + col]);
                }
                C[(size_t)row * N + col] = f2bb(v);
            }
        }
    }
}

// ---------------------------------------------------------------------------
// Prep kernels
__global__ __launch_bounds__(256) void conv_x(const float* __restrict__ in,
                                              ushortb* __restrict__ out)
{
    size_t i4 = (size_t)blockIdx.x * 256 + threadIdx.x;
    float4 v = *(const float4*)(in + i4 * 4);
    ushort4 o;
    o.x = f2bb(v.x); o.y = f2bb(v.y); o.z = f2bb(v.z); o.w = f2bb(v.w);
    *(ushort4*)(out + i4 * 4) = o;
}

__global__ __launch_bounds__(256) void conv_t(const float* __restrict__ W,
                                              ushortb* __restrict__ Wt, int N, int K)
{
    int idx = blockIdx.x * 256 + threadIdx.x;    // n*K + k
    int n = idx / K, k = idx - n * K;
    Wt[idx] = f2bb(W[(size_t)k * N + n]);
}

__global__ __launch_bounds__(256) void repack_t(const float* __restrict__ W,
                                                ushortb* __restrict__ Wt, float scale)
{
    int idx = blockIdx.x * 256 + threadIdx.x;    // n*512 + k
    int n = idx >> 9, k = idx & 511;
    int h = n >> 7, e = n & 127;
    Wt[idx] = f2bb(W[(size_t)(h * 512 + k) * 128 + e] * scale);
}

__global__ __launch_bounds__(256) void pe_kernel(float* __restrict__ pe)
{
    int idx = blockIdx.x * 256 + threadIdx.x;    // s*512 + c
    int s = idx >> 9, c = idx & 511;
    float div = expf((float)(c & ~1) * (-9.210340371976184f / 512.0f));
    float ang = (float)s * div;
    pe[idx] = (c & 1) ? cosf(ang) : sinf(ang);
}

// ---------------------------------------------------------------------------
// MFMA flash attention, transposed-score orientation.
// QK^T computed as mfma(A=K_tile, B=Q) -> D[row=t=quad*4+reg][col=q=l15]:
// each lane owns ONE q-column -> softmax reductions are register trees +
// 2 shuffles; alpha is 1 exp/lane; oacc rescale skipped when no max changed.
__global__ __launch_bounds__(256) void attn_mfma(
    const ushortb* __restrict__ Qb, const ushortb* __restrict__ Kb,
    const ushortb* __restrict__ Vt, ushortb* __restrict__ O)
{
    __shared__ ushortb sK[32][136];
    __shared__ ushortb sVt[128][40];
    __shared__ ushortb sP[4][16][40];   // [wave][q][t]

    const int tid = threadIdx.x;
    const int wave = tid >> 6, lane = tid & 63;
    const int quad = lane >> 4, l15 = lane & 15;
    const int b = blockIdx.z, h = blockIdx.y;
    const int q0 = blockIdx.x * 64 + wave * 16;
    const size_t qk_off = ((size_t)b << 10) * 512 + h * 128;
    const ushortb* Qp = Qb + qk_off;
    const ushortb* Kp = Kb + qk_off;
    const ushortb* Vp = Vt + (((size_t)(b * 4 + h)) << 17);

    short8 qfrag[4];   // B-frag: Q[q=l15][k=quad*8+j]
    {
        const ushortb* qrow = Qp + (size_t)(q0 + l15) * 512;
        #pragma unroll
        for (int kc = 0; kc < 4; ++kc)
            qfrag[kc] = *(const short8*)(qrow + kc * 32 + quad * 8);
    }

    f32x4 oacc[8];
    #pragma unroll
    for (int dt = 0; dt < 8; ++dt) oacc[dt] = (f32x4){0.f, 0.f, 0.f, 0.f};
    float m_old = -3.0e38f;   // per-lane, q = l15
    float l_sum = 0.f;

    for (int t0 = 0; t0 < 1024; t0 += 32) {
        __syncthreads();
        #pragma unroll
        for (int c = 0; c < 2; ++c) {
            int idx = c * 2048 + tid * 8;
            int t = idx >> 7, d0 = idx & 127;
            *(short8*)&sK[t][d0] = *(const short8*)(Kp + (size_t)(t0 + t) * 512 + d0);
        }
        #pragma unroll
        for (int c = 0; c < 2; ++c) {
            int idx = c * 256 + tid;
            int d = idx >> 2, toff = (idx & 3) * 8;
            *(short8*)&sVt[d][toff] = *(const short8*)(Vp + ((size_t)d << 10) + t0 + toff);
        }
        __syncthreads();

        // S^T: D[t][q], t = quad*4+reg (+0/16), q = l15
        f32x4 sacc0 = {0.f, 0.f, 0.f, 0.f}, sacc1 = {0.f, 0.f, 0.f, 0.f};
        #pragma unroll
        for (int kc = 0; kc < 4; ++kc) {
            short8 k0f = *(const short8*)&sK[l15][kc * 32 + quad * 8];
            short8 k1f = *(const short8*)&sK[16 + l15][kc * 32 + quad * 8];
            sacc0 = __builtin_amdgcn_mfma_f32_16x16x32_bf16(k0f, qfrag[kc], sacc0, 0, 0, 0);
            sacc1 = __builtin_amdgcn_mfma_f32_16x16x32_bf16(k1f, qfrag[kc], sacc1, 0, 0, 0);
        }

        // per-lane online softmax for q = l15
        float vm = fmaxf(fmaxf(fmaxf(sacc0[0], sacc0[1]), fmaxf(sacc0[2], sacc0[3])),
                         fmaxf(fmaxf(sacc1[0], sacc1[1]), fmaxf(sacc1[2], sacc1[3])));
        vm = fmaxf(vm, __shfl_xor(vm, 16));
        vm = fmaxf(vm, __shfl_xor(vm, 32));
        float mnew = fmaxf(m_old, vm);
        float alpha = __expf(m_old - mnew);
        bool changed = mnew > m_old;
        m_old = mnew;

        float p0[4], p1[4], s = 0.f;
        #pragma unroll
        for (int r = 0; r < 4; ++r) {
            p0[r] = __expf(sacc0[r] - mnew);
            p1[r] = __expf(sacc1[r] - mnew);
            s += p0[r] + p1[r];
        }
        s += __shfl_xor(s, 16);
        s += __shfl_xor(s, 32);
        l_sum = l_sum * alpha + s;

        // store P[q][t] (bf16) for the PV A-frag
        ushort4 w0, w1;
        w0.x = f2bb(p0[0]); w0.y = f2bb(p0[1]); w0.z = f2bb(p0[2]); w0.w = f2bb(p0[3]);
        w1.x = f2bb(p1[0]); w1.y = f2bb(p1[1]); w1.z = f2bb(p1[2]); w1.w = f2bb(p1[3]);
        *(ushort4*)&sP[wave][l15][quad * 4]      = w0;
        *(ushort4*)&sP[wave][l15][16 + quad * 4] = w1;

        // rescale O accumulator only when some row max moved (wave-uniform)
        if (__any(changed)) {
            float ar[4];
            #pragma unroll
            for (int r = 0; r < 4; ++r) ar[r] = __shfl(alpha, quad * 4 + r);
            #pragma unroll
            for (int dt = 0; dt < 8; ++dt)
                #pragma unroll
                for (int r = 0; r < 4; ++r) oacc[dt][r] *= ar[r];
        }

        // A-frag: P[q=l15][t=quad*8+j]  (same-wave LDS round trip)
        short8 pfrag = *(const short8*)&sP[wave][l15][quad * 8];

        #pragma unroll
        for (int dt = 0; dt < 8; ++dt) {
            short8 vfrag = *(const short8*)&sVt[dt * 16 + l15][quad * 8];
            oacc[dt] = __builtin_amdgcn_mfma_f32_16x16x32_bf16(pfrag, vfrag, oacc[dt], 0, 0, 0);
        }
    }

    // epilogue: oacc D[row=q=quad*4+reg][col=d=l15]; l_sum lives at lane q
    const size_t obase = (((size_t)(b * 4 + h) << 10) + q0) << 7;
    #pragma unroll
    for (int r = 0; r < 4; ++r) {
        float lr = __shfl(l_sum, quad * 4 + r);
        float invl = 1.0f / lr;
        int q = quad * 4 + r;
        #pragma unroll
        for (int dt = 0; dt < 8; ++dt)
            O[obase + ((size_t)q << 7) + dt * 16 + l15] = f2bb(oacc[dt][r] * invl);
    }
}

// ---------------------------------------------------------------------------
// LayerNorm over 512 features, bf16 in/out (vectorized 2-wide), fp32 math.
__global__ __launch_bounds__(256) void ln_kernel(const ushortb* __restrict__ in,
                                                 const float* __restrict__ g,
                                                 const float* __restrict__ bta,
                                                 ushortb* __restrict__ out)
{
    const size_t row = blockIdx.x;
    const int tid = threadIdx.x;
    unsigned u = *(const unsigned*)&in[row * 512 + tid * 2];
    float v0 = bb2f((ushortb)(u & 0xffffu));
    float v1 = bb2f((ushortb)(u >> 16));
    __shared__ float ss[256], sq[256];
    ss[tid] = v0 + v1;
    sq[tid] = v0 * v0 + v1 * v1;
    __syncthreads();
    for (int o = 128; o > 0; o >>= 1) {
        if (tid < o) { ss[tid] += ss[tid + o]; sq[tid] += sq[tid + o]; }
        __syncthreads();
    }
    float mu = ss[0] * (1.0f / 512.0f);
    float var = sq[0] * (1.0f / 512.0f) - mu * mu;
    float rstd = rsqrtf(var + 1e-5f);
    float e0 = (v0 - mu) * rstd * g[tid * 2]     + bta[tid * 2];
    float e1 = (v1 - mu) * rstd * g[tid * 2 + 1] + bta[tid * 2 + 1];
    unsigned o = (unsigned)f2bb(e0) | ((unsigned)f2bb(e1) << 16);
    *(unsigned*)&out[row * 512 + tid * 2] = o;
}

// ---------------------------------------------------------------------------
// MaxPool1d(16) + FC[32768,2] partial: grid (16 batch, 16 chunks), atomicAdd.
__global__ __launch_bounds__(256) void final_partial(const ushortb* __restrict__ ln2,
                                                     const float* __restrict__ fcw,
                                                     float* __restrict__ zbuf)
{
    const int b = blockIdx.x, chunk = blockIdx.y;
    const int tid = threadIdx.x;
    float a0 = 0.0f, a1 = 0.0f;
    #pragma unroll
    for (int t = 0; t < 8; ++t) {
        int m = chunk * 2048 + t * 256 + tid;
        int s = m >> 5, j = m & 31;
        const ushortb* p = ln2 + (((size_t)(b * 1024 + s)) << 9) + j * 16;
        float mx = -1e30f;
        #pragma unroll
        for (int e = 0; e < 16; ++e) mx = fmaxf(mx, bb2f(p[e]));
        a0 += mx * fcw[2 * m];
        a1 += mx * fcw[2 * m + 1];
    }
    __shared__ float r0[256], r1[256];
    r0[tid] = a0; r1[tid] = a1;
    __syncthreads();
    for (int o = 128; o > 0; o >>= 1) {
        if (tid < o) { r0[tid] += r0[tid + o]; r1[tid] += r1[tid + o]; }
        __syncthreads();
    }
    if (tid == 0) {
        atomicAdd(&zbuf[2 * b],     r0[0]);
        atomicAdd(&zbuf[2 * b + 1], r1[0]);
    }
}

__global__ __launch_bounds__(64) void final_logits(const float* __restrict__ zbuf,
                                                   const float* __restrict__ fcb,
                                                   float* __restrict__ out)
{
    int b = threadIdx.x;
    if (b < 16) {
        float z0 = zbuf[2 * b]     + fcb[0];
        float z1 = zbuf[2 * b + 1] + fcb[1];
        float mx = fmaxf(z0, z1);
        float lse = mx + logf(expf(z0 - mx) + expf(z1 - mx));
        out[2 * b]     = z0 - lse;
        out[2 * b + 1] = z1 - lse;
    }
}

// ---------------------------------------------------------------------------
extern "C" void kernel_launch(void* const* d_in, const int* in_sizes, int n_in,
                              void* d_out, int out_size, void* d_ws, size_t ws_size,
                              hipStream_t stream)
{
    const float* x     = (const float*)d_in[0];
    const float* emb_w = (const float*)d_in[1];
    const float* emb_b = (const float*)d_in[2];
    const float* WQ    = (const float*)d_in[3];
    const float* WK    = (const float*)d_in[4];
    const float* WV    = (const float*)d_in[5];
    const float* WO    = (const float*)d_in[6];
    const float* g1    = (const float*)d_in[7];
    const float* b1    = (const float*)d_in[8];
    const float* l1w   = (const float*)d_in[9];
    const float* l1b   = (const float*)d_in[10];
    const float* l2w   = (const float*)d_in[11];
    const float* l2b   = (const float*)d_in[12];
    const float* g2    = (const float*)d_in[13];
    const float* b2    = (const float*)d_in[14];
    const float* fcw   = (const float*)d_in[15];
    const float* fcb   = (const float*)d_in[16];
    float* out = (float*)d_out;

    char* ws = (char*)d_ws;
    const size_t Ub = (size_t)16384 * 512 * 2;   // 16.78 MB bf16 activation unit
    // u0: xb -> r1 -> r2       u1: h0b -> ln2     u2: Qb -> ln1
    // u3: Kb -> mid[0]         u4: Vt -> mid[1]   u5: headR -> mid[2]   u6: mid[3]
    ushortb* xb    = (ushortb*)(ws + 0 * Ub);
    ushortb* h0b   = (ushortb*)(ws + 1 * Ub);
    ushortb* Qb    = (ushortb*)(ws + 2 * Ub);
    ushortb* Kb    = (ushortb*)(ws + 3 * Ub);
    ushortb* Vt    = (ushortb*)(ws + 4 * Ub);
    ushortb* headR = (ushortb*)(ws + 5 * Ub);
    ushortb* mid   = (ushortb*)(ws + 3 * Ub);    // [16384,2048] over u3..u6
    ushortb* r1    = xb;
    ushortb* ln1   = Qb;
    ushortb* r2    = xb;
    ushortb* ln2   = h0b;
    char* wb = ws + 7 * Ub;
    ushortb* embwt = (ushortb*)(wb);                       // [512][512]
    ushortb* wqt   = (ushortb*)(wb + 1 * 524288);
    ushortb* wkt   = (ushortb*)(wb + 2 * 524288);
    ushortb* wvt   = (ushortb*)(wb + 3 * 524288);
    ushortb* wot   = (ushortb*)(wb + 4 * 524288);
    ushortb* l1wt  = (ushortb*)(wb + 5 * 524288);          // [2048][512]
    ushortb* l2wt  = (ushortb*)(wb + 9 * 524288);          // [512][2048]
    float*   pe    = (float*)  (wb + 13 * 524288);         // [1024][512] fp32
    float*   zbuf  = (float*)  (wb + 13 * 524288 + 2097152);  // [16][2]

    const int M = 16384;

    // prep
    conv_x<<<8192, 256, 0, stream>>>(x, xb);
    pe_kernel<<<2048, 256, 0, stream>>>(pe);
    conv_t<<<1024, 256, 0, stream>>>(emb_w, embwt, 512, 512);
    repack_t<<<1024, 256, 0, stream>>>(WQ, wqt, 0.08838834764831845f);
    repack_t<<<1024, 256, 0, stream>>>(WK, wkt, 1.0f);
    repack_t<<<1024, 256, 0, stream>>>(WV, wvt, 1.0f);
    conv_t<<<1024, 256, 0, stream>>>(WO, wot, 512, 512);
    conv_t<<<4096, 256, 0, stream>>>(l1w, l1wt, 2048, 512);
    conv_t<<<4096, 256, 0, stream>>>(l2w, l2wt, 512, 2048);
    hipMemsetAsync(zbuf, 0, 16 * 2 * sizeof(float), stream);

    // 1) h0 = x @ emb_w + emb_b + pe
    gemm_mfma<EP_EMB><<<dim3(M / 128, 4), 256, 0, stream>>>(
        xb, embwt, emb_b, nullptr, pe, h0b, M, 512, 512);

    // 2) Q/K/V projections (Q scale baked into wqt); V stored transposed
    gemm_mfma<EP_NONE><<<dim3(M / 128, 4), 256, 0, stream>>>(
        h0b, wqt, nullptr, nullptr, nullptr, Qb, M, 512, 512);
    gemm_mfma<EP_NONE><<<dim3(M / 128, 4), 256, 0, stream>>>(
        h0b, wkt, nullptr, nullptr, nullptr, Kb, M, 512, 512);
    gemm_mfma<EP_VT><<<dim3(M / 128, 4), 256, 0, stream>>>(
        h0b, wvt, nullptr, nullptr, nullptr, Vt, M, 512, 512);

    // 3) flash attention -> headR bf16 ([B,H,S,DK] flat == raw reshape)
    attn_mfma<<<dim3(16, 4, 16), 256, 0, stream>>>(Qb, Kb, Vt, headR);

    // 4) r1 = headR @ WO + h0 ; ln1 = LN(r1)
    gemm_mfma<EP_RES><<<dim3(M / 128, 4), 256, 0, stream>>>(
        headR, wot, nullptr, h0b, nullptr, r1, M, 512, 512);
    ln_kernel<<<M, 256, 0, stream>>>(r1, g1, b1, ln1);

    // 5) FFN
    gemm_mfma<EP_BIAS_RELU><<<dim3(M / 128, 16), 256, 0, stream>>>(
        ln1, l1wt, l1b, nullptr, nullptr, mid, M, 2048, 512);
    gemm_mfma<EP_BIAS_RES><<<dim3(M / 128, 4), 256, 0, stream>>>(
        mid, l2wt, l2b, ln1, nullptr, r2, M, 512, 2048);
    ln_kernel<<<M, 256, 0, stream>>>(r2, g2, b2, ln2);

    // 6) maxpool + FC + log_softmax (two-stage, 256-block parallel)
    final_partial<<<dim3(16, 16), 256, 0, stream>>>(ln2, fcw, zbuf);
    final_logits<<<1, 64, 0, stream>>>(zbuf, fcb, out);
}

// Round 8
// 405.976 us; speedup vs baseline: 12.3034x; 1.1769x over previous
//
#include <hip/hip_runtime.h>

typedef unsigned short ushortb;
typedef __attribute__((ext_vector_type(8))) short short8;    // 8 bf16 = 16B (MFMA A/B frag)
typedef __attribute__((ext_vector_type(4))) float f32x4;     // MFMA C/D frag

__device__ __forceinline__ ushortb f2bb(float f) {
    union { float f; unsigned u; } x; x.f = f;
    unsigned r = x.u + 0x7fffu + ((x.u >> 16) & 1u);   // RNE
    return (ushortb)(r >> 16);
}
__device__ __forceinline__ float bb2f(ushortb u) {
    union { unsigned u; float f; } x; x.u = ((unsigned)u) << 16; return x.f;
}

// async global->LDS DMA, 16B per lane; lds base wave-uniform, lane -> base+lane*16
__device__ __forceinline__ void async_ld16(void* lds, const void* g) {
    __builtin_amdgcn_global_load_lds(
        (const __attribute__((address_space(1))) void*)g,
        (__attribute__((address_space(3))) void*)lds, 16, 0, 0);
}

// ---------------------------------------------------------------------------
#define EP_EMB       0   // + bias + pe table
#define EP_RES       2   // + bf16 residual
#define EP_BIAS_RELU 3   // + bias, relu
#define EP_BIAS_RES  4   // + bias + bf16 residual
#define EP_QKV       7   // N=1536 fused: cols<1024 -> Qb/Kb, cols>=1024 -> Vt transposed

// C[M,N] = A[M,K] @ Bt[N,K]^T (+ epilogue). bf16 in, fp32 MFMA accum, bf16 out.
// Block 256 thr (4 waves, 2x2), tile 128x128, BK=32, global_load_lds staging,
// XOR-swizzled unpadded LDS (slot ^ (r^(r>>2))&3) -> <=2-way banks (free).
template <int EP>
__global__ __launch_bounds__(256) void gemm_mfma(
    const ushortb* __restrict__ A, const ushortb* __restrict__ Bt,
    const float* __restrict__ bias, const ushortb* __restrict__ res,
    const float* __restrict__ pe, ushortb* __restrict__ C,
    int M, int N, int K)
{
    __shared__ ushortb sA[128][32];
    __shared__ ushortb sB[128][32];

    const int tid = threadIdx.x;
    const int wave = tid >> 6, lane = tid & 63;
    const int quad = lane >> 4, l15 = lane & 15;
    const int row0 = blockIdx.x * 128;
    const int col0 = blockIdx.y * 128;
    const int wm = (wave >> 1) * 64, wn = (wave & 1) * 64;
    const int srl = lane >> 2, slot = lane & 3;

    f32x4 acc[4][4];
    #pragma unroll
    for (int i = 0; i < 4; ++i)
        #pragma unroll
        for (int j = 0; j < 4; ++j) acc[i][j] = (f32x4){0.f, 0.f, 0.f, 0.f};

    for (int k0 = 0; k0 < K; k0 += 32) {
        __syncthreads();
        #pragma unroll
        for (int c = 0; c < 2; ++c) {
            int rbase = wave * 32 + c * 16;
            int r = rbase + srl;
            int ka = (slot ^ ((r ^ (r >> 2)) & 3)) * 8;
            async_ld16(&sA[rbase][0], A  + (size_t)(row0 + r) * K + k0 + ka);
            async_ld16(&sB[rbase][0], Bt + (size_t)(col0 + r) * K + k0 + ka);
        }
        __syncthreads();

        short8 af[4], bf[4];
        #pragma unroll
        for (int i = 0; i < 4; ++i) {
            int m = wm + i * 16 + l15;
            af[i] = *(const short8*)&sA[m][(quad ^ ((m ^ (m >> 2)) & 3)) * 8];
        }
        #pragma unroll
        for (int j = 0; j < 4; ++j) {
            int n = wn + j * 16 + l15;
            bf[j] = *(const short8*)&sB[n][(quad ^ ((n ^ (n >> 2)) & 3)) * 8];
        }
        #pragma unroll
        for (int i = 0; i < 4; ++i)
            #pragma unroll
            for (int j = 0; j < 4; ++j)
                acc[i][j] = __builtin_amdgcn_mfma_f32_16x16x32_bf16(af[i], bf[j], acc[i][j], 0, 0, 0);
    }

    if constexpr (EP == EP_QKV) {
        if (col0 < 1024) {
            // Q (cols 0..511) or K (512..1023); Qb/Kb are consecutive M*512 buffers
            ushortb* dst = C + ((size_t)(col0 >> 9)) * ((size_t)M * 512);
            #pragma unroll
            for (int i = 0; i < 4; ++i) {
                #pragma unroll
                for (int r = 0; r < 4; ++r) {
                    int row = row0 + wm + i * 16 + quad * 4 + r;
                    #pragma unroll
                    for (int j = 0; j < 4; ++j) {
                        int col = (col0 + wn + j * 16 + l15) & 511;
                        dst[(size_t)row * 512 + col] = f2bb(acc[i][j][r]);
                    }
                }
            }
        } else {
            // V: row=b*1024+s, vcol=h*128+e -> Vt[(b*4+h)*128+e][s]
            ushortb* Vt = C + (size_t)2 * M * 512;
            int bb = row0 >> 10;
            #pragma unroll
            for (int i = 0; i < 4; ++i) {
                int s = (row0 & 1023) + wm + i * 16 + quad * 4;
                #pragma unroll
                for (int j = 0; j < 4; ++j) {
                    int vcol = col0 + wn + j * 16 + l15 - 1024;
                    int h = vcol >> 7, e = vcol & 127;
                    ushort4 v;
                    v.x = f2bb(acc[i][j][0]); v.y = f2bb(acc[i][j][1]);
                    v.z = f2bb(acc[i][j][2]); v.w = f2bb(acc[i][j][3]);
                    *(ushort4*)&Vt[((size_t)((bb * 4 + h) * 128 + e) << 10) + s] = v;
                }
            }
        }
        return;
    }

    #pragma unroll
    for (int i = 0; i < 4; ++i) {
        #pragma unroll
        for (int r = 0; r < 4; ++r) {
            int row = row0 + wm + i * 16 + quad * 4 + r;
            #pragma unroll
            for (int j = 0; j < 4; ++j) {
                int col = col0 + wn + j * 16 + l15;
                float v = acc[i][j][r];
                if constexpr (EP == EP_EMB) {
                    v += bias[col] + pe[((row & 1023) << 9) + col];
                } else if constexpr (EP == EP_RES) {
                    v += bb2f(res[(size_t)row * N + col]);
                } else if constexpr (EP == EP_BIAS_RELU) {
                    v = fmaxf(v + bias[col], 0.0f);
                } else if constexpr (EP == EP_BIAS_RES) {
                    v += bias[col] + bb2f(res[(size_t)row * N + col]);
                }
                C[(size_t)row * N + col] = f2bb(v);
            }
        }
    }
}

// ---------------------------------------------------------------------------
// Prep: x fp32 -> bf16
__global__ __launch_bounds__(256) void conv_x(const float* __restrict__ in,
                                              ushortb* __restrict__ out)
{
    size_t i4 = (size_t)blockIdx.x * 256 + threadIdx.x;
    float4 v = *(const float4*)(in + i4 * 4);
    ushort4 o;
    o.x = f2bb(v.x); o.y = f2bb(v.y); o.z = f2bb(v.z); o.w = f2bb(v.w);
    *(ushort4*)(out + i4 * 4) = o;
}

// LDS-tiled transpose-convert: in fp32 [R][C] (+z*R*C) -> out bf16 [C][R] (+z*R*C), *scale.
// Both global sides coalesced; LDS stride 65 dwords -> 2-way banks (free).
__global__ __launch_bounds__(256) void tileT(const float* __restrict__ in,
                                             ushortb* __restrict__ out,
                                             int R, int C, float scale)
{
    __shared__ float t[64][65];
    const int tx = threadIdx.x & 63, ty = threadIdx.x >> 6;
    const int c0 = blockIdx.x * 64, r0 = blockIdx.y * 64;
    const size_t zoff = (size_t)blockIdx.z * R * C;
    #pragma unroll
    for (int i = 0; i < 16; ++i) {
        int r = ty + i * 4;
        t[r][tx] = in[zoff + (size_t)(r0 + r) * C + c0 + tx] * scale;
    }
    __syncthreads();
    #pragma unroll
    for (int i = 0; i < 16; ++i) {
        int r = ty + i * 4;
        out[zoff + (size_t)(c0 + r) * R + r0 + tx] = f2bb(t[tx][r]);
    }
}

// positional encoding table fp32 [1024][512]
__global__ __launch_bounds__(256) void pe_kernel(float* __restrict__ pe)
{
    int idx = blockIdx.x * 256 + threadIdx.x;    // s*512 + c
    int s = idx >> 9, c = idx & 511;
    float div = expf((float)(c & ~1) * (-9.210340371976184f / 512.0f));
    float ang = (float)s * div;
    pe[idx] = (c & 1) ? cosf(ang) : sinf(ang);
}

// ---------------------------------------------------------------------------
// MFMA flash attention, fixed-max softmax (shift-invariance; scores bounded so
// exp2 never overflows: |s*log2e| <~ 20, l_sum < 3e8 in fp32). Q pre-scaled by
// log2e/sqrt(128) so p = exp2(score). Block = 128 q rows (32/wave), t tiles of 32.
// Qb/Kb bf16 [B*S,512] (+h*128), Vt bf16 [(b*4+h)*128+e][1024]. O bf16 [B,H,S,DK].
__global__ __launch_bounds__(256) void attn_mfma(
    const ushortb* __restrict__ Qb, const ushortb* __restrict__ Kb,
    const ushortb* __restrict__ Vt, ushortb* __restrict__ O)
{
    __shared__ ushortb sK[32][136];
    __shared__ ushortb sVt[128][40];
    __shared__ ushortb sP[4][32][40];   // [wave][q_local][t]

    const int tid = threadIdx.x;
    const int wave = tid >> 6, lane = tid & 63;
    const int quad = lane >> 4, l15 = lane & 15;
    const int b = blockIdx.z, h = blockIdx.y;
    const int q0 = blockIdx.x * 128 + wave * 32;
    const size_t qk_off = ((size_t)b << 10) * 512 + h * 128;
    const ushortb* Qp = Qb + qk_off;
    const ushortb* Kp = Kb + qk_off;
    const ushortb* Vp = Vt + (((size_t)(b * 4 + h)) << 17);

    short8 qfA[4], qfB[4];   // B-frags: Q[q=l15 | 16+l15][k=quad*8+j]
    {
        const ushortb* qa = Qp + (size_t)(q0 + l15) * 512;
        const ushortb* qb = Qp + (size_t)(q0 + 16 + l15) * 512;
        #pragma unroll
        for (int kc = 0; kc < 4; ++kc) {
            qfA[kc] = *(const short8*)(qa + kc * 32 + quad * 8);
            qfB[kc] = *(const short8*)(qb + kc * 32 + quad * 8);
        }
    }

    f32x4 oA[8], oB[8];
    #pragma unroll
    for (int dt = 0; dt < 8; ++dt) {
        oA[dt] = (f32x4){0.f, 0.f, 0.f, 0.f};
        oB[dt] = (f32x4){0.f, 0.f, 0.f, 0.f};
    }
    float lA = 0.f, lB = 0.f;   // per-lane partial denominators (q = l15 / 16+l15)

    for (int t0 = 0; t0 < 1024; t0 += 32) {
        __syncthreads();
        #pragma unroll
        for (int c = 0; c < 2; ++c) {
            int idx = c * 2048 + tid * 8;
            int t = idx >> 7, d0 = idx & 127;
            *(short8*)&sK[t][d0] = *(const short8*)(Kp + (size_t)(t0 + t) * 512 + d0);
        }
        #pragma unroll
        for (int c = 0; c < 2; ++c) {
            int idx = c * 256 + tid;
            int d = idx >> 2, toff = (idx & 3) * 8;
            *(short8*)&sVt[d][toff] = *(const short8*)(Vp + ((size_t)d << 10) + t0 + toff);
        }
        __syncthreads();

        // S^T: D[t][q]; col=q(l15 in group), row t = quad*4+reg (+0/16)
        f32x4 sA0 = {0,0,0,0}, sA1 = {0,0,0,0}, sB0 = {0,0,0,0}, sB1 = {0,0,0,0};
        #pragma unroll
        for (int kc = 0; kc < 4; ++kc) {
            short8 k0f = *(const short8*)&sK[l15][kc * 32 + quad * 8];
            short8 k1f = *(const short8*)&sK[16 + l15][kc * 32 + quad * 8];
            sA0 = __builtin_amdgcn_mfma_f32_16x16x32_bf16(k0f, qfA[kc], sA0, 0, 0, 0);
            sA1 = __builtin_amdgcn_mfma_f32_16x16x32_bf16(k1f, qfA[kc], sA1, 0, 0, 0);
            sB0 = __builtin_amdgcn_mfma_f32_16x16x32_bf16(k0f, qfB[kc], sB0, 0, 0, 0);
            sB1 = __builtin_amdgcn_mfma_f32_16x16x32_bf16(k1f, qfB[kc], sB1, 0, 0, 0);
        }

        // fixed-max softmax: p = 2^score (log2e baked into Q scale)
        float pA0[4], pA1[4], pB0[4], pB1[4];
        float sumA = 0.f, sumB = 0.f;
        #pragma unroll
        for (int r = 0; r < 4; ++r) {
            pA0[r] = exp2f(sA0[r]); pA1[r] = exp2f(sA1[r]);
            pB0[r] = exp2f(sB0[r]); pB1[r] = exp2f(sB1[r]);
            sumA += pA0[r] + pA1[r];
            sumB += pB0[r] + pB1[r];
        }
        lA += sumA; lB += sumB;

        ushort4 w;
        w.x = f2bb(pA0[0]); w.y = f2bb(pA0[1]); w.z = f2bb(pA0[2]); w.w = f2bb(pA0[3]);
        *(ushort4*)&sP[wave][l15][quad * 4] = w;
        w.x = f2bb(pA1[0]); w.y = f2bb(pA1[1]); w.z = f2bb(pA1[2]); w.w = f2bb(pA1[3]);
        *(ushort4*)&sP[wave][l15][16 + quad * 4] = w;
        w.x = f2bb(pB0[0]); w.y = f2bb(pB0[1]); w.z = f2bb(pB0[2]); w.w = f2bb(pB0[3]);
        *(ushort4*)&sP[wave][16 + l15][quad * 4] = w;
        w.x = f2bb(pB1[0]); w.y = f2bb(pB1[1]); w.z = f2bb(pB1[2]); w.w = f2bb(pB1[3]);
        *(ushort4*)&sP[wave][16 + l15][16 + quad * 4] = w;

        // A-frags: P[q_local = l15 | 16+l15][t = quad*8+j] (same-wave LDS RT)
        short8 pfA = *(const short8*)&sP[wave][l15][quad * 8];
        short8 pfB = *(const short8*)&sP[wave][16 + l15][quad * 8];

        #pragma unroll
        for (int dt = 0; dt < 8; ++dt) {
            short8 vfrag = *(const short8*)&sVt[dt * 16 + l15][quad * 8];
            oA[dt] = __builtin_amdgcn_mfma_f32_16x16x32_bf16(pfA, vfrag, oA[dt], 0, 0, 0);
            oB[dt] = __builtin_amdgcn_mfma_f32_16x16x32_bf16(pfB, vfrag, oB[dt], 0, 0, 0);
        }
    }

    // reduce denominators across quads (lane bits 4,5); then all lanes hold
    // the total for their own l15 column.
    lA += __shfl_xor(lA, 16); lA += __shfl_xor(lA, 32);
    lB += __shfl_xor(lB, 16); lB += __shfl_xor(lB, 32);

    const size_t obase = (((size_t)(b * 4 + h) << 10) + q0) << 7;
    #pragma unroll
    for (int r = 0; r < 4; ++r) {
        float invA = 1.0f / __shfl(lA, quad * 4 + r);
        float invB = 1.0f / __shfl(lB, quad * 4 + r);
        int qa = quad * 4 + r, qb = 16 + quad * 4 + r;
        #pragma unroll
        for (int dt = 0; dt < 8; ++dt) {
            O[obase + ((size_t)qa << 7) + dt * 16 + l15] = f2bb(oA[dt][r] * invA);
            O[obase + ((size_t)qb << 7) + dt * 16 + l15] = f2bb(oB[dt][r] * invB);
        }
    }
}

// ---------------------------------------------------------------------------
// LayerNorm over 512 features: wave per row, 8 elems/lane, shuffle reduce.
__global__ __launch_bounds__(256) void ln_kernel(const ushortb* __restrict__ in,
                                                 const float* __restrict__ g,
                                                 const float* __restrict__ bta,
                                                 ushortb* __restrict__ out)
{
    const int lane = threadIdx.x & 63, w = threadIdx.x >> 6;
    const size_t row = (size_t)blockIdx.x * 4 + w;
    const int e0 = lane * 8;
    short8 v8 = *(const short8*)(in + row * 512 + e0);
    float v[8];
    #pragma unroll
    for (int k = 0; k < 8; ++k) v[k] = bb2f((ushortb)((short*)&v8)[k]);
    float s = 0.f, sq = 0.f;
    #pragma unroll
    for (int k = 0; k < 8; ++k) { s += v[k]; sq += v[k] * v[k]; }
    #pragma unroll
    for (int o = 1; o < 64; o <<= 1) { s += __shfl_xor(s, o); sq += __shfl_xor(sq, o); }
    float mu = s * (1.0f / 512.0f);
    float var = sq * (1.0f / 512.0f) - mu * mu;
    float rstd = rsqrtf(var + 1e-5f);
    float4 g0 = *(const float4*)(g + e0),  g1 = *(const float4*)(g + e0 + 4);
    float4 b0 = *(const float4*)(bta + e0), b1 = *(const float4*)(bta + e0 + 4);
    float gg[8] = {g0.x, g0.y, g0.z, g0.w, g1.x, g1.y, g1.z, g1.w};
    float bb[8] = {b0.x, b0.y, b0.z, b0.w, b1.x, b1.y, b1.z, b1.w};
    short8 o8;
    #pragma unroll
    for (int k = 0; k < 8; ++k)
        ((short*)&o8)[k] = (short)f2bb((v[k] - mu) * rstd * gg[k] + bb[k]);
    *(short8*)(out + row * 512 + e0) = o8;
}

// ---------------------------------------------------------------------------
// MaxPool1d(16) + FC[32768,2] partial: grid (16 batch, 16 chunks), atomicAdd.
__global__ __launch_bounds__(256) void final_partial(const ushortb* __restrict__ ln2,
                                                     const float* __restrict__ fcw,
                                                     float* __restrict__ zbuf)
{
    const int b = blockIdx.x, chunk = blockIdx.y;
    const int tid = threadIdx.x;
    float a0 = 0.0f, a1 = 0.0f;
    #pragma unroll
    for (int t = 0; t < 8; ++t) {
        int m = chunk * 2048 + t * 256 + tid;
        int s = m >> 5, j = m & 31;
        const ushortb* p = ln2 + (((size_t)(b * 1024 + s)) << 9) + j * 16;
        float mx = -1e30f;
        #pragma unroll
        for (int e = 0; e < 16; ++e) mx = fmaxf(mx, bb2f(p[e]));
        a0 += mx * fcw[2 * m];
        a1 += mx * fcw[2 * m + 1];
    }
    __shared__ float r0[256], r1[256];
    r0[tid] = a0; r1[tid] = a1;
    __syncthreads();
    for (int o = 128; o > 0; o >>= 1) {
        if (tid < o) { r0[tid] += r0[tid + o]; r1[tid] += r1[tid + o]; }
        __syncthreads();
    }
    if (tid == 0) {
        atomicAdd(&zbuf[2 * b],     r0[0]);
        atomicAdd(&zbuf[2 * b + 1], r1[0]);
    }
}

__global__ __launch_bounds__(64) void final_logits(const float* __restrict__ zbuf,
                                                   const float* __restrict__ fcb,
                                                   float* __restrict__ out)
{
    int b = threadIdx.x;
    if (b < 16) {
        float z0 = zbuf[2 * b]     + fcb[0];
        float z1 = zbuf[2 * b + 1] + fcb[1];
        float mx = fmaxf(z0, z1);
        float lse = mx + logf(expf(z0 - mx) + expf(z1 - mx));
        out[2 * b]     = z0 - lse;
        out[2 * b + 1] = z1 - lse;
    }
}

// ---------------------------------------------------------------------------
extern "C" void kernel_launch(void* const* d_in, const int* in_sizes, int n_in,
                              void* d_out, int out_size, void* d_ws, size_t ws_size,
                              hipStream_t stream)
{
    const float* x     = (const float*)d_in[0];
    const float* emb_w = (const float*)d_in[1];
    const float* emb_b = (const float*)d_in[2];
    const float* WQ    = (const float*)d_in[3];
    const float* WK    = (const float*)d_in[4];
    const float* WV    = (const float*)d_in[5];
    const float* WO    = (const float*)d_in[6];
    const float* g1    = (const float*)d_in[7];
    const float* b1    = (const float*)d_in[8];
    const float* l1w   = (const float*)d_in[9];
    const float* l1b   = (const float*)d_in[10];
    const float* l2w   = (const float*)d_in[11];
    const float* l2b   = (const float*)d_in[12];
    const float* g2    = (const float*)d_in[13];
    const float* b2    = (const float*)d_in[14];
    const float* fcw   = (const float*)d_in[15];
    const float* fcb   = (const float*)d_in[16];
    float* out = (float*)d_out;

    char* ws = (char*)d_ws;
    const size_t Ub = (size_t)16384 * 512 * 2;   // 16.78 MB bf16 activation unit
    // u0: xb -> r1 -> r2   u1: h0b -> ln2   u2: Qb -> ln1
    // u3: Kb -> mid[0]     u4: Vt -> mid[1] u5: headR -> mid[2]  u6: mid[3]
    ushortb* xb    = (ushortb*)(ws + 0 * Ub);
    ushortb* h0b   = (ushortb*)(ws + 1 * Ub);
    ushortb* Qb    = (ushortb*)(ws + 2 * Ub);   // Kb = Qb + M*512, Vt = Qb + 2*M*512
    ushortb* Kb    = (ushortb*)(ws + 3 * Ub);
    ushortb* Vt    = (ushortb*)(ws + 4 * Ub);
    ushortb* headR = (ushortb*)(ws + 5 * Ub);
    ushortb* mid   = (ushortb*)(ws + 3 * Ub);   // [16384,2048] over u3..u6
    ushortb* r1    = xb;
    ushortb* ln1   = Qb;
    ushortb* r2    = xb;
    ushortb* ln2   = h0b;
    char* wb = ws + 7 * Ub;
    ushortb* embwt = (ushortb*)(wb);                        // [512][512]
    ushortb* wqkvt = (ushortb*)(wb + 524288);               // [1536][512]
    ushortb* wot   = (ushortb*)(wb + 2097152);              // [512][512]
    ushortb* l1wt  = (ushortb*)(wb + 2621440);              // [2048][512]
    ushortb* l2wt  = (ushortb*)(wb + 4718592);              // [512][2048]
    float*   pe    = (float*)  (wb + 6815744);              // [1024][512] fp32
    float*   zbuf  = (float*)  (wb + 8912896);              // [16][2]

    const int M = 16384;
    const float qscale = 0.12753139626997592f;  // log2(e)/sqrt(128)

    // prep
    conv_x<<<8192, 256, 0, stream>>>(x, xb);
    pe_kernel<<<2048, 256, 0, stream>>>(pe);
    tileT<<<dim3(8, 8, 1),  256, 0, stream>>>(emb_w, embwt, 512, 512, 1.0f);
    tileT<<<dim3(2, 8, 4),  256, 0, stream>>>(WQ, wqkvt,               512, 128, qscale);
    tileT<<<dim3(2, 8, 4),  256, 0, stream>>>(WK, wqkvt + 262144,      512, 128, 1.0f);
    tileT<<<dim3(2, 8, 4),  256, 0, stream>>>(WV, wqkvt + 524288,      512, 128, 1.0f);
    tileT<<<dim3(8, 8, 1),  256, 0, stream>>>(WO, wot, 512, 512, 1.0f);
    tileT<<<dim3(32, 8, 1), 256, 0, stream>>>(l1w, l1wt, 512, 2048, 1.0f);
    tileT<<<dim3(8, 32, 1), 256, 0, stream>>>(l2w, l2wt, 2048, 512, 1.0f);
    hipMemsetAsync(zbuf, 0, 16 * 2 * sizeof(float), stream);

    // 1) h0 = x @ emb_w + emb_b + pe
    gemm_mfma<EP_EMB><<<dim3(M / 128, 4), 256, 0, stream>>>(
        xb, embwt, emb_b, nullptr, pe, h0b, M, 512, 512);

    // 2) fused QKV projection (Q scale baked; V transposed in epilogue)
    gemm_mfma<EP_QKV><<<dim3(M / 128, 12), 256, 0, stream>>>(
        h0b, wqkvt, nullptr, nullptr, nullptr, Qb, M, 1536, 512);

    // 3) flash attention -> headR bf16 ([B,H,S,DK] flat == raw reshape)
    attn_mfma<<<dim3(8, 4, 16), 256, 0, stream>>>(Qb, Kb, Vt, headR);

    // 4) r1 = headR @ WO + h0 ; ln1 = LN(r1)
    gemm_mfma<EP_RES><<<dim3(M / 128, 4), 256, 0, stream>>>(
        headR, wot, nullptr, h0b, nullptr, r1, M, 512, 512);
    ln_kernel<<<M / 4, 256, 0, stream>>>(r1, g1, b1, ln1);

    // 5) FFN
    gemm_mfma<EP_BIAS_RELU><<<dim3(M / 128, 16), 256, 0, stream>>>(
        ln1, l1wt, l1b, nullptr, nullptr, mid, M, 2048, 512);
    gemm_mfma<EP_BIAS_RES><<<dim3(M / 128, 4), 256, 0, stream>>>(
        mid, l2wt, l2b, ln1, nullptr, r2, M, 512, 2048);
    ln_kernel<<<M / 4, 256, 0, stream>>>(r2, g2, b2, ln2);

    // 6) maxpool + FC + log_softmax
    final_partial<<<dim3(16, 16), 256, 0, stream>>>(ln2, fcw, zbuf);
    final_logits<<<1, 64, 0, stream>>>(zbuf, fcb, out);
}

// Round 9
// 390.442 us; speedup vs baseline: 12.7929x; 1.0398x over previous
//
#include <hip/hip_runtime.h>

typedef unsigned short ushortb;
typedef __attribute__((ext_vector_type(8))) short short8;    // 8 bf16 = 16B (MFMA A/B frag)
typedef __attribute__((ext_vector_type(4))) float f32x4;     // MFMA C/D frag

__device__ __forceinline__ ushortb f2bb(float f) {
    union { float f; unsigned u; } x; x.f = f;
    unsigned r = x.u + 0x7fffu + ((x.u >> 16) & 1u);   // RNE
    return (ushortb)(r >> 16);
}
__device__ __forceinline__ float bb2f(ushortb u) {
    union { unsigned u; float f; } x; x.u = ((unsigned)u) << 16; return x.f;
}

// async global->LDS DMA, 16B per lane; lds base wave-uniform, lane -> base+lane*16
__device__ __forceinline__ void async_ld16(void* lds, const void* g) {
    __builtin_amdgcn_global_load_lds(
        (const __attribute__((address_space(1))) void*)g,
        (__attribute__((address_space(3))) void*)lds, 16, 0, 0);
}

// ---------------------------------------------------------------------------
#define EP_EMB       0   // + bias + pe table
#define EP_RES       2   // + bf16 residual
#define EP_BIAS_RELU 3   // + bias, relu
#define EP_BIAS_RES  4   // + bias + bf16 residual
#define EP_QKV       7   // N=1536 fused: cols<1024 -> Qb/Kb, cols>=1024 -> Vt transposed

// C[M,N] = A[M,K] @ Bt[N,K]^T (+ epilogue). bf16 in, fp32 MFMA accum, bf16 out.
// Block 256 thr (4 waves, 2x2), tile 128x128, BK=64 (8 barriers for K=512),
// global_load_lds staging, XOR-swizzled unpadded LDS:
//   LDS chunk c of row r holds global 16B-chunk c ^ ((r^(r>>3))&7)
// -> staging is linear DMA; fragment reads spread 8 lanes/bank-group (floor).
template <int EP>
__global__ __launch_bounds__(256) void gemm_mfma(
    const ushortb* __restrict__ A, const ushortb* __restrict__ Bt,
    const float* __restrict__ bias, const ushortb* __restrict__ res,
    const float* __restrict__ pe, ushortb* __restrict__ C,
    int M, int N, int K)
{
    __shared__ ushortb sA[128][64];   // 16 KB
    __shared__ ushortb sB[128][64];   // 16 KB

    const int tid = threadIdx.x;
    const int wave = tid >> 6, lane = tid & 63;
    const int quad = lane >> 4, l15 = lane & 15;
    const int row0 = blockIdx.x * 128;
    const int col0 = blockIdx.y * 128;
    const int wm = (wave >> 1) * 64, wn = (wave & 1) * 64;
    const int srl = lane >> 3, slot = lane & 7;

    f32x4 acc[4][4];
    #pragma unroll
    for (int i = 0; i < 4; ++i)
        #pragma unroll
        for (int j = 0; j < 4; ++j) acc[i][j] = (f32x4){0.f, 0.f, 0.f, 0.f};

    for (int k0 = 0; k0 < K; k0 += 64) {
        __syncthreads();
        // stage A/B tiles [128][64]: per wave 4 calls x 1KB each per operand
        #pragma unroll
        for (int c = 0; c < 4; ++c) {
            int rbase = wave * 32 + c * 8;
            int r = rbase + srl;
            int ka = (slot ^ ((r ^ (r >> 3)) & 7)) * 8;
            async_ld16(&sA[rbase][0], A  + (size_t)(row0 + r) * K + k0 + ka);
            async_ld16(&sB[rbase][0], Bt + (size_t)(col0 + r) * K + k0 + ka);
        }
        __syncthreads();   // drains vmcnt -> tiles resident

        #pragma unroll
        for (int kc = 0; kc < 2; ++kc) {
            short8 af[4], bf[4];
            #pragma unroll
            for (int i = 0; i < 4; ++i) {
                int m = wm + i * 16 + l15;
                af[i] = *(const short8*)&sA[m][(((kc * 4 + quad) ^ ((m ^ (m >> 3)) & 7))) * 8];
            }
            #pragma unroll
            for (int j = 0; j < 4; ++j) {
                int n = wn + j * 16 + l15;
                bf[j] = *(const short8*)&sB[n][(((kc * 4 + quad) ^ ((n ^ (n >> 3)) & 7))) * 8];
            }
            #pragma unroll
            for (int i = 0; i < 4; ++i)
                #pragma unroll
                for (int j = 0; j < 4; ++j)
                    acc[i][j] = __builtin_amdgcn_mfma_f32_16x16x32_bf16(af[i], bf[j], acc[i][j], 0, 0, 0);
        }
    }

    if constexpr (EP == EP_QKV) {
        if (col0 < 1024) {
            // Q (cols 0..511) or K (512..1023); Qb/Kb are consecutive M*512 buffers
            ushortb* dst = C + ((size_t)(col0 >> 9)) * ((size_t)M * 512);
            #pragma unroll
            for (int i = 0; i < 4; ++i) {
                #pragma unroll
                for (int r = 0; r < 4; ++r) {
                    int row = row0 + wm + i * 16 + quad * 4 + r;
                    #pragma unroll
                    for (int j = 0; j < 4; ++j) {
                        int col = (col0 + wn + j * 16 + l15) & 511;
                        dst[(size_t)row * 512 + col] = f2bb(acc[i][j][r]);
                    }
                }
            }
        } else {
            // V: row=b*1024+s, vcol=h*128+e -> Vt[(b*4+h)*128+e][s]
            ushortb* Vt = C + (size_t)2 * M * 512;
            int bb = row0 >> 10;
            #pragma unroll
            for (int i = 0; i < 4; ++i) {
                int s = (row0 & 1023) + wm + i * 16 + quad * 4;
                #pragma unroll
                for (int j = 0; j < 4; ++j) {
                    int vcol = col0 + wn + j * 16 + l15 - 1024;
                    int h = vcol >> 7, e = vcol & 127;
                    ushort4 v;
                    v.x = f2bb(acc[i][j][0]); v.y = f2bb(acc[i][j][1]);
                    v.z = f2bb(acc[i][j][2]); v.w = f2bb(acc[i][j][3]);
                    *(ushort4*)&Vt[((size_t)((bb * 4 + h) * 128 + e) << 10) + s] = v;
                }
            }
        }
        return;
    }

    #pragma unroll
    for (int i = 0; i < 4; ++i) {
        #pragma unroll
        for (int r = 0; r < 4; ++r) {
            int row = row0 + wm + i * 16 + quad * 4 + r;
            #pragma unroll
            for (int j = 0; j < 4; ++j) {
                int col = col0 + wn + j * 16 + l15;
                float v = acc[i][j][r];
                if constexpr (EP == EP_EMB) {
                    v += bias[col] + pe[((row & 1023) << 9) + col];
                } else if constexpr (EP == EP_RES) {
                    v += bb2f(res[(size_t)row * N + col]);
                } else if constexpr (EP == EP_BIAS_RELU) {
                    v = fmaxf(v + bias[col], 0.0f);
                } else if constexpr (EP == EP_BIAS_RES) {
                    v += bias[col] + bb2f(res[(size_t)row * N + col]);
                }
                C[(size_t)row * N + col] = f2bb(v);
            }
        }
    }
}

// ---------------------------------------------------------------------------
// Prep: x fp32 -> bf16
__global__ __launch_bounds__(256) void conv_x(const float* __restrict__ in,
                                              ushortb* __restrict__ out)
{
    size_t i4 = (size_t)blockIdx.x * 256 + threadIdx.x;
    float4 v = *(const float4*)(in + i4 * 4);
    ushort4 o;
    o.x = f2bb(v.x); o.y = f2bb(v.y); o.z = f2bb(v.z); o.w = f2bb(v.w);
    *(ushort4*)(out + i4 * 4) = o;
}

// LDS-tiled transpose-convert: in fp32 [R][C] (+z*R*C) -> out bf16 [C][R] (+z*R*C), *scale.
__global__ __launch_bounds__(256) void tileT(const float* __restrict__ in,
                                             ushortb* __restrict__ out,
                                             int R, int C, float scale)
{
    __shared__ float t[64][65];
    const int tx = threadIdx.x & 63, ty = threadIdx.x >> 6;
    const int c0 = blockIdx.x * 64, r0 = blockIdx.y * 64;
    const size_t zoff = (size_t)blockIdx.z * R * C;
    #pragma unroll
    for (int i = 0; i < 16; ++i) {
        int r = ty + i * 4;
        t[r][tx] = in[zoff + (size_t)(r0 + r) * C + c0 + tx] * scale;
    }
    __syncthreads();
    #pragma unroll
    for (int i = 0; i < 16; ++i) {
        int r = ty + i * 4;
        out[zoff + (size_t)(c0 + r) * R + r0 + tx] = f2bb(t[tx][r]);
    }
}

// positional encoding table fp32 [1024][512]
__global__ __launch_bounds__(256) void pe_kernel(float* __restrict__ pe)
{
    int idx = blockIdx.x * 256 + threadIdx.x;    // s*512 + c
    int s = idx >> 9, c = idx & 511;
    float div = expf((float)(c & ~1) * (-9.210340371976184f / 512.0f));
    float ang = (float)s * div;
    pe[idx] = (c & 1) ? cosf(ang) : sinf(ang);
}

// ---------------------------------------------------------------------------
// MFMA flash attention, fixed-max softmax (verified R8). Q pre-scaled by
// log2(e)/sqrt(128) so p = exp2(score); scores bounded -> no overflow.
// Block = 128 q rows (32/wave), t tiles of 32.
__global__ __launch_bounds__(256) void attn_mfma(
    const ushortb* __restrict__ Qb, const ushortb* __restrict__ Kb,
    const ushortb* __restrict__ Vt, ushortb* __restrict__ O)
{
    __shared__ ushortb sK[32][136];
    __shared__ ushortb sVt[128][40];
    __shared__ ushortb sP[4][32][40];   // [wave][q_local][t]

    const int tid = threadIdx.x;
    const int wave = tid >> 6, lane = tid & 63;
    const int quad = lane >> 4, l15 = lane & 15;
    const int b = blockIdx.z, h = blockIdx.y;
    const int q0 = blockIdx.x * 128 + wave * 32;
    const size_t qk_off = ((size_t)b << 10) * 512 + h * 128;
    const ushortb* Qp = Qb + qk_off;
    const ushortb* Kp = Kb + qk_off;
    const ushortb* Vp = Vt + (((size_t)(b * 4 + h)) << 17);

    short8 qfA[4], qfB[4];   // B-frags: Q[q=l15 | 16+l15][k=quad*8+j]
    {
        const ushortb* qa = Qp + (size_t)(q0 + l15) * 512;
        const ushortb* qb = Qp + (size_t)(q0 + 16 + l15) * 512;
        #pragma unroll
        for (int kc = 0; kc < 4; ++kc) {
            qfA[kc] = *(const short8*)(qa + kc * 32 + quad * 8);
            qfB[kc] = *(const short8*)(qb + kc * 32 + quad * 8);
        }
    }

    f32x4 oA[8], oB[8];
    #pragma unroll
    for (int dt = 0; dt < 8; ++dt) {
        oA[dt] = (f32x4){0.f, 0.f, 0.f, 0.f};
        oB[dt] = (f32x4){0.f, 0.f, 0.f, 0.f};
    }
    float lA = 0.f, lB = 0.f;

    for (int t0 = 0; t0 < 1024; t0 += 32) {
        __syncthreads();
        #pragma unroll
        for (int c = 0; c < 2; ++c) {
            int idx = c * 2048 + tid * 8;
            int t = idx >> 7, d0 = idx & 127;
            *(short8*)&sK[t][d0] = *(const short8*)(Kp + (size_t)(t0 + t) * 512 + d0);
        }
        #pragma unroll
        for (int c = 0; c < 2; ++c) {
            int idx = c * 256 + tid;
            int d = idx >> 2, toff = (idx & 3) * 8;
            *(short8*)&sVt[d][toff] = *(const short8*)(Vp + ((size_t)d << 10) + t0 + toff);
        }
        __syncthreads();

        f32x4 sA0 = {0,0,0,0}, sA1 = {0,0,0,0}, sB0 = {0,0,0,0}, sB1 = {0,0,0,0};
        #pragma unroll
        for (int kc = 0; kc < 4; ++kc) {
            short8 k0f = *(const short8*)&sK[l15][kc * 32 + quad * 8];
            short8 k1f = *(const short8*)&sK[16 + l15][kc * 32 + quad * 8];
            sA0 = __builtin_amdgcn_mfma_f32_16x16x32_bf16(k0f, qfA[kc], sA0, 0, 0, 0);
            sA1 = __builtin_amdgcn_mfma_f32_16x16x32_bf16(k1f, qfA[kc], sA1, 0, 0, 0);
            sB0 = __builtin_amdgcn_mfma_f32_16x16x32_bf16(k0f, qfB[kc], sB0, 0, 0, 0);
            sB1 = __builtin_amdgcn_mfma_f32_16x16x32_bf16(k1f, qfB[kc], sB1, 0, 0, 0);
        }

        float pA0[4], pA1[4], pB0[4], pB1[4];
        float sumA = 0.f, sumB = 0.f;
        #pragma unroll
        for (int r = 0; r < 4; ++r) {
            pA0[r] = exp2f(sA0[r]); pA1[r] = exp2f(sA1[r]);
            pB0[r] = exp2f(sB0[r]); pB1[r] = exp2f(sB1[r]);
            sumA += pA0[r] + pA1[r];
            sumB += pB0[r] + pB1[r];
        }
        lA += sumA; lB += sumB;

        ushort4 w;
        w.x = f2bb(pA0[0]); w.y = f2bb(pA0[1]); w.z = f2bb(pA0[2]); w.w = f2bb(pA0[3]);
        *(ushort4*)&sP[wave][l15][quad * 4] = w;
        w.x = f2bb(pA1[0]); w.y = f2bb(pA1[1]); w.z = f2bb(pA1[2]); w.w = f2bb(pA1[3]);
        *(ushort4*)&sP[wave][l15][16 + quad * 4] = w;
        w.x = f2bb(pB0[0]); w.y = f2bb(pB0[1]); w.z = f2bb(pB0[2]); w.w = f2bb(pB0[3]);
        *(ushort4*)&sP[wave][16 + l15][quad * 4] = w;
        w.x = f2bb(pB1[0]); w.y = f2bb(pB1[1]); w.z = f2bb(pB1[2]); w.w = f2bb(pB1[3]);
        *(ushort4*)&sP[wave][16 + l15][16 + quad * 4] = w;

        short8 pfA = *(const short8*)&sP[wave][l15][quad * 8];
        short8 pfB = *(const short8*)&sP[wave][16 + l15][quad * 8];

        #pragma unroll
        for (int dt = 0; dt < 8; ++dt) {
            short8 vfrag = *(const short8*)&sVt[dt * 16 + l15][quad * 8];
            oA[dt] = __builtin_amdgcn_mfma_f32_16x16x32_bf16(pfA, vfrag, oA[dt], 0, 0, 0);
            oB[dt] = __builtin_amdgcn_mfma_f32_16x16x32_bf16(pfB, vfrag, oB[dt], 0, 0, 0);
        }
    }

    lA += __shfl_xor(lA, 16); lA += __shfl_xor(lA, 32);
    lB += __shfl_xor(lB, 16); lB += __shfl_xor(lB, 32);

    const size_t obase = (((size_t)(b * 4 + h) << 10) + q0) << 7;
    #pragma unroll
    for (int r = 0; r < 4; ++r) {
        float invA = 1.0f / __shfl(lA, quad * 4 + r);
        float invB = 1.0f / __shfl(lB, quad * 4 + r);
        int qa = quad * 4 + r, qb = 16 + quad * 4 + r;
        #pragma unroll
        for (int dt = 0; dt < 8; ++dt) {
            O[obase + ((size_t)qa << 7) + dt * 16 + l15] = f2bb(oA[dt][r] * invA);
            O[obase + ((size_t)qb << 7) + dt * 16 + l15] = f2bb(oB[dt][r] * invB);
        }
    }
}

// ---------------------------------------------------------------------------
// LayerNorm over 512 features: wave per row, 8 elems/lane, shuffle reduce.
__global__ __launch_bounds__(256) void ln_kernel(const ushortb* __restrict__ in,
                                                 const float* __restrict__ g,
                                                 const float* __restrict__ bta,
                                                 ushortb* __restrict__ out)
{
    const int lane = threadIdx.x & 63, w = threadIdx.x >> 6;
    const size_t row = (size_t)blockIdx.x * 4 + w;
    const int e0 = lane * 8;
    short8 v8 = *(const short8*)(in + row * 512 + e0);
    float v[8];
    #pragma unroll
    for (int k = 0; k < 8; ++k) v[k] = bb2f((ushortb)((short*)&v8)[k]);
    float s = 0.f, sq = 0.f;
    #pragma unroll
    for (int k = 0; k < 8; ++k) { s += v[k]; sq += v[k] * v[k]; }
    #pragma unroll
    for (int o = 1; o < 64; o <<= 1) { s += __shfl_xor(s, o); sq += __shfl_xor(sq, o); }
    float mu = s * (1.0f / 512.0f);
    float var = sq * (1.0f / 512.0f) - mu * mu;
    float rstd = rsqrtf(var + 1e-5f);
    float4 g0 = *(const float4*)(g + e0),  g1 = *(const float4*)(g + e0 + 4);
    float4 b0 = *(const float4*)(bta + e0), b1 = *(const float4*)(bta + e0 + 4);
    float gg[8] = {g0.x, g0.y, g0.z, g0.w, g1.x, g1.y, g1.z, g1.w};
    float bb[8] = {b0.x, b0.y, b0.z, b0.w, b1.x, b1.y, b1.z, b1.w};
    short8 o8;
    #pragma unroll
    for (int k = 0; k < 8; ++k)
        ((short*)&o8)[k] = (short)f2bb((v[k] - mu) * rstd * gg[k] + bb[k]);
    *(short8*)(out + row * 512 + e0) = o8;
}

// ---------------------------------------------------------------------------
// MaxPool1d(16) + FC[32768,2] partial: grid (16 batch, 16 chunks), atomicAdd.
__global__ __launch_bounds__(256) void final_partial(const ushortb* __restrict__ ln2,
                                                     const float* __restrict__ fcw,
                                                     float* __restrict__ zbuf)
{
    const int b = blockIdx.x, chunk = blockIdx.y;
    const int tid = threadIdx.x;
    float a0 = 0.0f, a1 = 0.0f;
    #pragma unroll
    for (int t = 0; t < 8; ++t) {
        int m = chunk * 2048 + t * 256 + tid;
        int s = m >> 5, j = m & 31;
        const ushortb* p = ln2 + (((size_t)(b * 1024 + s)) << 9) + j * 16;
        float mx = -1e30f;
        #pragma unroll
        for (int e = 0; e < 16; ++e) mx = fmaxf(mx, bb2f(p[e]));
        a0 += mx * fcw[2 * m];
        a1 += mx * fcw[2 * m + 1];
    }
    __shared__ float r0[256], r1[256];
    r0[tid] = a0; r1[tid] = a1;
    __syncthreads();
    for (int o = 128; o > 0; o >>= 1) {
        if (tid < o) { r0[tid] += r0[tid + o]; r1[tid] += r1[tid + o]; }
        __syncthreads();
    }
    if (tid == 0) {
        atomicAdd(&zbuf[2 * b],     r0[0]);
        atomicAdd(&zbuf[2 * b + 1], r1[0]);
    }
}

__global__ __launch_bounds__(64) void final_logits(const float* __restrict__ zbuf,
                                                   const float* __restrict__ fcb,
                                                   float* __restrict__ out)
{
    int b = threadIdx.x;
    if (b < 16) {
        float z0 = zbuf[2 * b]     + fcb[0];
        float z1 = zbuf[2 * b + 1] + fcb[1];
        float mx = fmaxf(z0, z1);
        float lse = mx + logf(expf(z0 - mx) + expf(z1 - mx));
        out[2 * b]     = z0 - lse;
        out[2 * b + 1] = z1 - lse;
    }
}

// ---------------------------------------------------------------------------
extern "C" void kernel_launch(void* const* d_in, const int* in_sizes, int n_in,
                              void* d_out, int out_size, void* d_ws, size_t ws_size,
                              hipStream_t stream)
{
    const float* x     = (const float*)d_in[0];
    const float* emb_w = (const float*)d_in[1];
    const float* emb_b = (const float*)d_in[2];
    const float* WQ    = (const float*)d_in[3];
    const float* WK    = (const float*)d_in[4];
    const float* WV    = (const float*)d_in[5];
    const float* WO    = (const float*)d_in[6];
    const float* g1    = (const float*)d_in[7];
    const float* b1    = (const float*)d_in[8];
    const float* l1w   = (const float*)d_in[9];
    const float* l1b   = (const float*)d_in[10];
    const float* l2w   = (const float*)d_in[11];
    const float* l2b   = (const float*)d_in[12];
    const float* g2    = (const float*)d_in[13];
    const float* b2    = (const float*)d_in[14];
    const float* fcw   = (const float*)d_in[15];
    const float* fcb   = (const float*)d_in[16];
    float* out = (float*)d_out;

    char* ws = (char*)d_ws;
    const size_t Ub = (size_t)16384 * 512 * 2;   // 16.78 MB bf16 activation unit
    // u0: xb -> r1 -> r2   u1: h0b -> ln2   u2: Qb -> ln1
    // u3: Kb -> mid[0]     u4: Vt -> mid[1] u5: headR -> mid[2]  u6: mid[3]
    ushortb* xb    = (ushortb*)(ws + 0 * Ub);
    ushortb* h0b   = (ushortb*)(ws + 1 * Ub);
    ushortb* Qb    = (ushortb*)(ws + 2 * Ub);   // Kb = Qb + M*512, Vt = Qb + 2*M*512
    ushortb* Kb    = (ushortb*)(ws + 3 * Ub);
    ushortb* Vt    = (ushortb*)(ws + 4 * Ub);
    ushortb* headR = (ushortb*)(ws + 5 * Ub);
    ushortb* mid   = (ushortb*)(ws + 3 * Ub);   // [16384,2048] over u3..u6
    ushortb* r1    = xb;
    ushortb* ln1   = Qb;
    ushortb* r2    = xb;
    ushortb* ln2   = h0b;
    char* wb = ws + 7 * Ub;
    ushortb* embwt = (ushortb*)(wb);                        // [512][512]
    ushortb* wqkvt = (ushortb*)(wb + 524288);               // [1536][512]
    ushortb* wot   = (ushortb*)(wb + 2097152);              // [512][512]
    ushortb* l1wt  = (ushortb*)(wb + 2621440);              // [2048][512]
    ushortb* l2wt  = (ushortb*)(wb + 4718592);              // [512][2048]
    float*   pe    = (float*)  (wb + 6815744);              // [1024][512] fp32
    float*   zbuf  = (float*)  (wb + 8912896);              // [16][2]

    const int M = 16384;
    const float qscale = 0.12753139626997592f;  // log2(e)/sqrt(128)

    // prep
    conv_x<<<8192, 256, 0, stream>>>(x, xb);
    pe_kernel<<<2048, 256, 0, stream>>>(pe);
    tileT<<<dim3(8, 8, 1),  256, 0, stream>>>(emb_w, embwt, 512, 512, 1.0f);
    tileT<<<dim3(2, 8, 4),  256, 0, stream>>>(WQ, wqkvt,               512, 128, qscale);
    tileT<<<dim3(2, 8, 4),  256, 0, stream>>>(WK, wqkvt + 262144,      512, 128, 1.0f);
    tileT<<<dim3(2, 8, 4),  256, 0, stream>>>(WV, wqkvt + 524288,      512, 128, 1.0f);
    tileT<<<dim3(8, 8, 1),  256, 0, stream>>>(WO, wot, 512, 512, 1.0f);
    tileT<<<dim3(32, 8, 1), 256, 0, stream>>>(l1w, l1wt, 512, 2048, 1.0f);
    tileT<<<dim3(8, 32, 1), 256, 0, stream>>>(l2w, l2wt, 2048, 512, 1.0f);
    hipMemsetAsync(zbuf, 0, 16 * 2 * sizeof(float), stream);

    // 1) h0 = x @ emb_w + emb_b + pe
    gemm_mfma<EP_EMB><<<dim3(M / 128, 4), 256, 0, stream>>>(
        xb, embwt, emb_b, nullptr, pe, h0b, M, 512, 512);

    // 2) fused QKV projection (Q scale baked; V transposed in epilogue)
    gemm_mfma<EP_QKV><<<dim3(M / 128, 12), 256, 0, stream>>>(
        h0b, wqkvt, nullptr, nullptr, nullptr, Qb, M, 1536, 512);

    // 3) flash attention -> headR bf16 ([B,H,S,DK] flat == raw reshape)
    attn_mfma<<<dim3(8, 4, 16), 256, 0, stream>>>(Qb, Kb, Vt, headR);

    // 4) r1 = headR @ WO + h0 ; ln1 = LN(r1)
    gemm_mfma<EP_RES><<<dim3(M / 128, 4), 256, 0, stream>>>(
        headR, wot, nullptr, h0b, nullptr, r1, M, 512, 512);
    ln_kernel<<<M / 4, 256, 0, stream>>>(r1, g1, b1, ln1);

    // 5) FFN
    gemm_mfma<EP_BIAS_RELU><<<dim3(M / 128, 16), 256, 0, stream>>>(
        ln1, l1wt, l1b, nullptr, nullptr, mid, M, 2048, 512);
    gemm_mfma<EP_BIAS_RES><<<dim3(M / 128, 4), 256, 0, stream>>>(
        mid, l2wt, l2b, ln1, nullptr, r2, M, 512, 2048);
    ln_kernel<<<M / 4, 256, 0, stream>>>(r2, g2, b2, ln2);

    // 6) maxpool + FC + log_softmax
    final_partial<<<dim3(16, 16), 256, 0, stream>>>(ln2, fcw, zbuf);
    final_logits<<<1, 64, 0, stream>>>(zbuf, fcb, out);
}